// Round 7
// baseline (459.588 us; speedup 1.0000x reference)
//
#include <hip/hip_runtime.h>
#include <cstdint>
#include <cstddef>

#define Nn    4096
#define Ee    131072
#define INC   512
#define HIDC  512
#define HEADS 4
#define NLAY  3
#define GG    16
#define FW    2048   // HEADS*HIDC

typedef __attribute__((ext_vector_type(8))) short bfrag;   // 8 bf16 (4 VGPRs)
typedef __attribute__((ext_vector_type(4))) float ffrag;   // 4 fp32 acc
typedef __attribute__((ext_vector_type(4))) uint uint4v;
typedef __attribute__((ext_vector_type(4))) float float4v;

__device__ __forceinline__ ushort f2bf(float v){
  uint u = __builtin_bit_cast(uint, v);
  u += 0x7fffu + ((u>>16)&1u);          // RNE
  return (ushort)(u>>16);
}
__device__ __forceinline__ float bf2f(ushort s){
  uint u = ((uint)s)<<16; return __builtin_bit_cast(float, u);
}
// acc[0..7] += w * unpack8(bf16x8 in uint4)
__device__ __forceinline__ void fma8(float* acc, uint4 g, float w){
  uint u[4] = {g.x, g.y, g.z, g.w};
  #pragma unroll
  for (int q=0;q<4;q++){
    float lo = __builtin_bit_cast(float, u[q]<<16);
    float hi = __builtin_bit_cast(float, u[q] & 0xffff0000u);
    acc[2*q]   += w*lo;
    acc[2*q+1] += w*hi;
  }
}
__device__ __forceinline__ void nt_store_u4(void* p, uint a, uint b, uint c, uint d){
  uint4v x = {a,b,c,d};
  __builtin_nontemporal_store(x, (uint4v*)p);
}
__device__ __forceinline__ void nt_store_f4(void* p, float a, float b, float c, float d){
  float4v x = {a,b,c,d};
  __builtin_nontemporal_store(x, (float4v*)p);
}
__device__ __forceinline__ void nt_pack8(void* p, const float* a){
  nt_store_u4(p,
    (uint)f2bf(a[0]) | ((uint)f2bf(a[1])<<16),
    (uint)f2bf(a[2]) | ((uint)f2bf(a[3])<<16),
    (uint)f2bf(a[4]) | ((uint)f2bf(a[5])<<16),
    (uint)f2bf(a[6]) | ((uint)f2bf(a[7])<<16));
}
// async global->LDS, 16B per lane; lds dest = wave-uniform base + lane*16
__device__ __forceinline__ void gload_lds16(const ushort* g, ushort* l){
  __builtin_amdgcn_global_load_lds(
      (const __attribute__((address_space(1))) void*)g,
      (__attribute__((address_space(3))) void*)l, 16, 0, 0);
}

// ---------------- fp32 -> bf16 elementwise ----------------
__global__ __launch_bounds__(256) void tobf(const float* __restrict__ X, ushort* __restrict__ Xb){
  int i = blockIdx.x*256 + threadIdx.x;
  Xb[i] = f2bf(X[i]);
}

// ---------------- batched 512x512 transpose -> bf16: W[b][r][c] -> T[b][c][r] ----------------
__global__ __launch_bounds__(256) void tbf(const float* __restrict__ W, ushort* __restrict__ T){
  __shared__ float tile[32][33];
  int b = blockIdx.z;
  int r0 = blockIdx.y*32, c0 = blockIdx.x*32;
  int t = threadIdx.x;
  int i = t>>3, j0 = (t&7)*4;
  const float* Wb = W + (size_t)b*512*512;
  float4 v = *(const float4*)(Wb + (size_t)(r0+i)*512 + c0 + j0);
  tile[i][j0]=v.x; tile[i][j0+1]=v.y; tile[i][j0+2]=v.z; tile[i][j0+3]=v.w;
  __syncthreads();
  ushort* o = T + (size_t)b*512*512 + (size_t)(c0+i)*512 + r0 + j0;
  #pragma unroll
  for (int q=0;q<4;q++) o[q] = f2bf(tile[j0+q][i]);
}

// ---------------- bf16 MFMA GEMM: C = A@B^T, 128x128 tile, async LDS staging ----------------
// LDS fragment-major [kquad][row][8 shorts]; wave w stages kquad w via global_load_lds:
//   lane l, call j -> row j*64+l, lds cell (w*128+j*64+l)*16B = base + lane*16. Conflict-free.
__global__ __launch_bounds__(256) void gemm_bf(
    const ushort* __restrict__ A, const ushort* __restrict__ B,
    const float* __restrict__ Res, float* __restrict__ Cf, ushort* __restrict__ Cb,
    int M, int N, int K, int relu_res)
{
  __shared__ __align__(16) ushort Ah[4096];   // 128 rows x 32 k = 8 KB
  __shared__ __align__(16) ushort Bh[4096];
  int t = threadIdx.x;
  int m0 = blockIdx.y*128, n0 = blockIdx.x*128;
  int wave = t>>6, lane = t&63;
  int wm = (wave&1)*64, wn = (wave>>1)*64;
  int lm = lane&15, quad = lane>>4;

  ffrag acc[4][4];
  #pragma unroll
  for (int i=0;i<4;i++){
    #pragma unroll
    for (int j=0;j<4;j++) acc[i][j] = (ffrag){0.f,0.f,0.f,0.f};
  }

  const ushort* gA0 = A + (size_t)(m0 + lane)*K      + wave*8;
  const ushort* gA1 = A + (size_t)(m0 + 64 + lane)*K + wave*8;
  const ushort* gB0 = B + (size_t)(n0 + lane)*K      + wave*8;
  const ushort* gB1 = B + (size_t)(n0 + 64 + lane)*K + wave*8;
  ushort* lA0 = &Ah[(wave*128     )*8];
  ushort* lA1 = &Ah[(wave*128 + 64)*8];
  ushort* lB0 = &Bh[(wave*128     )*8];
  ushort* lB1 = &Bh[(wave*128 + 64)*8];

  for (int k0 = 0; k0 < K; k0 += 32){
    gload_lds16(gA0 + k0, lA0);
    gload_lds16(gA1 + k0, lA1);
    gload_lds16(gB0 + k0, lB0);
    gload_lds16(gB1 + k0, lB1);
    __syncthreads();                 // drains vmcnt: LDS tiles ready
    bfrag af[4];
    #pragma unroll
    for (int mt=0; mt<4; mt++)
      af[mt] = *(const bfrag*)&Ah[(quad*128 + wm + mt*16 + lm)*8];
    #pragma unroll
    for (int nt=0; nt<4; nt++){
      bfrag bf = *(const bfrag*)&Bh[(quad*128 + wn + nt*16 + lm)*8];
      #pragma unroll
      for (int mt=0; mt<4; mt++)
        acc[mt][nt] = __builtin_amdgcn_mfma_f32_16x16x32_bf16(af[mt], bf, acc[mt][nt], 0,0,0);
    }
    __syncthreads();                 // all reads done before next overwrite
  }

  #pragma unroll
  for (int mt=0; mt<4; mt++){
    #pragma unroll
    for (int nt=0; nt<4; nt++){
      #pragma unroll
      for (int r=0;r<4;r++){
        int grow = m0 + wm + mt*16 + quad*4 + r;
        int gcol = n0 + wn + nt*16 + lm;
        size_t off = (size_t)grow*N + gcol;
        float v = acc[mt][nt][r];
        if (relu_res) v = fmaxf(v,0.f) + Res[off];
        if (Cf) __builtin_nontemporal_store(v, &Cf[off]);
        if (Cb) __builtin_nontemporal_store(f2bf(v), &Cb[off]);
      }
    }
  }
}

// ---------------- attention logits per (node,head) ----------------
__global__ __launch_bounds__(256) void compute_lg(const ushort* __restrict__ hbf,
    const float* __restrict__ a_src, const float* __restrict__ a_dst,
    float* __restrict__ lgs, float* __restrict__ lgd){
  int n = blockIdx.x; int t = threadIdx.x;
  int hd = t>>6, lane = t&63;
  uint4 g = *(const uint4*)(hbf + (size_t)n*FW + hd*HIDC + lane*8);
  float h[8] = {0,0,0,0,0,0,0,0};
  fma8(h, g, 1.0f);
  float4 as0 = *(const float4*)(a_src + hd*HIDC + lane*8);
  float4 as1 = *(const float4*)(a_src + hd*HIDC + lane*8 + 4);
  float4 ad0 = *(const float4*)(a_dst + hd*HIDC + lane*8);
  float4 ad1 = *(const float4*)(a_dst + hd*HIDC + lane*8 + 4);
  float s1 = h[0]*as0.x + h[1]*as0.y + h[2]*as0.z + h[3]*as0.w
           + h[4]*as1.x + h[5]*as1.y + h[6]*as1.z + h[7]*as1.w;
  float s2 = h[0]*ad0.x + h[1]*ad0.y + h[2]*ad0.z + h[3]*ad0.w
           + h[4]*ad1.x + h[5]*ad1.y + h[6]*ad1.z + h[7]*ad1.w;
  for (int off=32; off; off>>=1){ s1 += __shfl_down(s1,off); s2 += __shfl_down(s2,off); }
  if (lane==0){ lgs[n*HEADS+hd]=s1; lgd[n*HEADS+hd]=s2; }
}

// ---------------- fused edge pass 1: in-degree hist + set-semantics dedup ----------------
__global__ __launch_bounds__(256) void edge_pass1(const int* __restrict__ src, const int* __restrict__ dst,
    int* __restrict__ indeg, unsigned int* __restrict__ bitmap,
    int* __restrict__ cnt_s, int* __restrict__ flag){
  int e = blockIdx.x*256+threadIdx.x; if (e>=Ee) return;
  int s = src[e], d = dst[e];
  atomicAdd(&indeg[d],1);
  unsigned int key = (unsigned int)s*Nn + (unsigned int)d;
  unsigned int bit = 1u<<(key&31);
  unsigned int old = atomicOr(&bitmap[key>>5], bit);
  int f = (old & bit) ? 0 : 1;
  flag[e] = f;
  if (f) atomicAdd(&cnt_s[s],1);
}

// ---------------- dual exclusive scan ----------------
__global__ __launch_bounds__(1024) void exscan2(const int* __restrict__ cnt0, int* __restrict__ rp0,
    const int* __restrict__ cnt1, int* __restrict__ rp1){
  const int* cnt = blockIdx.x ? cnt1 : cnt0;
  int* rowptr    = blockIdx.x ? rp1  : rp0;
  __shared__ int sums[1024];
  int t = threadIdx.x;
  int v[4]; int s=0;
  #pragma unroll
  for (int i=0;i<4;i++){ int idx=t*4+i; v[i] = cnt[idx]; s+=v[i]; }
  sums[t]=s; __syncthreads();
  for (int off=1; off<1024; off<<=1){
    int other = (t>=off)? sums[t-off] : 0;
    __syncthreads();
    sums[t] += other;
    __syncthreads();
  }
  int run = (t>0)? sums[t-1] : 0;
  #pragma unroll
  for (int i=0;i<4;i++){ int idx=t*4+i; rowptr[idx]=run; run+=v[i]; }
  if (t==1023) rowptr[Nn]=sums[1023];
}

__global__ __launch_bounds__(256) void compute_dinv(const int* __restrict__ cnt, float* __restrict__ dinv){
  int n = blockIdx.x*256+threadIdx.x; if (n<Nn) dinv[n] = 1.0f/sqrtf((float)(1+cnt[n]));
}

// ---------------- fused edge pass 2: scatter dst-CSR (src vals) + src-CSR (col,dinv) ----------------
__global__ __launch_bounds__(256) void edge_pass2(const int* __restrict__ src, const int* __restrict__ dst,
    const int* __restrict__ flag,
    const int* __restrict__ rp_d, int* __restrict__ fill_d, int* __restrict__ slist,
    const int* __restrict__ rp_s, int* __restrict__ fill_s, int2* __restrict__ cw,
    const float* __restrict__ dinv){
  int e = blockIdx.x*256+threadIdx.x; if (e>=Ee) return;
  int s = src[e], d = dst[e];
  int p = atomicAdd(&fill_d[d],1); slist[rp_d[d]+p] = s;
  if (flag[e]){
    int q = atomicAdd(&fill_s[s],1);
    cw[rp_s[s]+q] = make_int2(d, __float_as_int(dinv[d]));
  }
}

// ---------------- GAT softmax-aggregate: block = (4 nodes) x (1 head), wave = node ----------------
__global__ __launch_bounds__(256) void gat_aggregate(const ushort* __restrict__ hbf,
    const float* __restrict__ lgs, const float* __restrict__ lgd,
    const int* __restrict__ rowptr, const int* __restrict__ slist,
    float* __restrict__ Hfeat, ushort* __restrict__ Hbf){
  int t = threadIdx.x;
  int wv = __builtin_amdgcn_readfirstlane(t>>6);
  int lane = t&63;
  int b = blockIdx.x;
  int hd = __builtin_amdgcn_readfirstlane(b & 3);
  int n = ((b>>2)<<2) + wv;
  int beg = rowptr[n], deg = rowptr[n+1]-beg;
  float ldst = lgd[n*HEADS+hd];
  // ---- single-pass online softmax (m,z) ----
  float m_ = -3.4e38f, z_ = 0.f;
  int   s0 = 0; float v0 = 0.f;
  for (int i=lane; i<deg; i+=64){
    int s = slist[beg+i];
    float v = lgs[s*HEADS+hd] + ldst;
    v = v>0.f ? v : 0.2f*v;
    if (i<64){ s0=s; v0=v; }
    float mn = fmaxf(m_, v);
    z_ = z_*__expf(m_-mn) + __expf(v-mn);
    m_ = mn;
  }
  for (int o=32;o;o>>=1){
    float mo = __shfl_down(m_,o), zo = __shfl_down(z_,o);
    float mn = fmaxf(m_, mo);
    z_ = z_*__expf(m_-mn) + zo*__expf(mo-mn);
    m_ = mn;
  }
  float mx = __shfl(m_,0);
  float zs = __shfl(z_,0);
  float inv = 1.f/(zs+1e-16f);
  // ---- weighted accumulate, 64-edge chunks, 8x-batched loads ----
  float acc[8] = {0,0,0,0,0,0,0,0};
  const ushort* hb = hbf + hd*HIDC + lane*8;
  for (int base=0; base<deg; base+=64){
    float al; int s;
    if (base==0){
      s = s0;
      al = (lane<deg) ? __expf(v0-mx)*inv : 0.f;
    } else {
      int i = base+lane;
      al = 0.f; s = 0;
      if (i<deg){
        s = slist[beg+i];
        float v = lgs[s*HEADS+hd] + ldst; v = v>0.f ? v : 0.2f*v;
        al = __expf(v-mx)*inv;
      }
    }
    int cn = min(64, deg-base);
    int c = 0;
    for (; c+8<=cn; c+=8){
      uint4 g[8]; float a[8];
      #pragma unroll
      for (int q=0;q<8;q++){
        a[q] = __shfl(al,c+q);
        int ss = __shfl(s,c+q);
        g[q] = *(const uint4*)(hb + (size_t)ss*FW);
      }
      #pragma unroll
      for (int q=0;q<8;q++) fma8(acc, g[q], a[q]);
    }
    for (; c+4<=cn; c+=4){
      uint4 g[4]; float a[4];
      #pragma unroll
      for (int q=0;q<4;q++){
        a[q] = __shfl(al,c+q);
        int ss = __shfl(s,c+q);
        g[q] = *(const uint4*)(hb + (size_t)ss*FW);
      }
      #pragma unroll
      for (int q=0;q<4;q++) fma8(acc, g[q], a[q]);
    }
    for (; c<cn; c++){
      float a = __shfl(al,c);
      int ss  = __shfl(s,c);
      uint4 g = *(const uint4*)(hb + (size_t)ss*FW);
      fma8(acc, g, a);
    }
  }
  size_t off = (size_t)n*FW + hd*HIDC + lane*8;
  nt_store_f4(Hfeat + off,     acc[0],acc[1],acc[2],acc[3]);
  nt_store_f4(Hfeat + off + 4, acc[4],acc[5],acc[6],acc[7]);
  nt_pack8(Hbf + off, acc);
}

// ---------------- SpMM: block = (4 nodes) x (1 chunk), chunk = blockIdx.x & 3 ----------------
__global__ __launch_bounds__(256) void spmm_bf(const ushort* __restrict__ Hbf,
    ushort* __restrict__ Phi,
    const int* __restrict__ rowptr, const int2* __restrict__ cw, const float* __restrict__ dinv){
  int t = threadIdx.x;
  int wv = __builtin_amdgcn_readfirstlane(t>>6);
  int lane = t&63;
  int b = blockIdx.x;
  int ck = __builtin_amdgcn_readfirstlane(b & 3);
  int n = ((b>>2)<<2) + wv;
  int f = (ck<<9) + lane*8;
  float di = dinv[n];
  float acc[8] = {0,0,0,0,0,0,0,0};
  const ushort* hb = Hbf + f;
  uint4 self = *(const uint4*)(hb + (size_t)n*FW);
  fma8(acc, self, di*di);
  int beg = rowptr[n], end = rowptr[n+1];
  for (int base=beg; base<end; base+=64){
    int i = base + lane;
    int m = n; float w = 0.f;
    if (i < end){ int2 e = cw[i]; m = e.x; w = di*__int_as_float(e.y); }
    int cn = min(64, end-base);
    int c = 0;
    for (; c+8<=cn; c+=8){
      uint4 g[8]; float ww[8];
      #pragma unroll
      for (int q=0;q<8;q++){
        ww[q] = __shfl(w,c+q);
        int mm = __shfl(m,c+q);
        g[q] = *(const uint4*)(hb + (size_t)mm*FW);
      }
      #pragma unroll
      for (int q=0;q<8;q++) fma8(acc, g[q], ww[q]);
    }
    for (; c+4<=cn; c+=4){
      uint4 g[4]; float ww[4];
      #pragma unroll
      for (int q=0;q<4;q++){
        ww[q] = __shfl(w,c+q);
        int mm = __shfl(m,c+q);
        g[q] = *(const uint4*)(hb + (size_t)mm*FW);
      }
      #pragma unroll
      for (int q=0;q<4;q++) fma8(acc, g[q], ww[q]);
    }
    for (; c<cn; c++){
      int mm   = __shfl(m,c);
      float ww = __shfl(w,c);
      uint4 g = *(const uint4*)(hb + (size_t)mm*FW);
      fma8(acc, g, ww);
    }
  }
  float a[8]; 
  #pragma unroll
  for (int q=0;q<8;q++) a[q]=acc[q];
  nt_pack8(Phi + (size_t)n*FW + f, a);
}

// ---------------- pooling ----------------
__global__ __launch_bounds__(256) void graph_offsets(const int* __restrict__ batch, int* __restrict__ goff){
  __shared__ int cnt[GG];
  int t = threadIdx.x;
  if (t<GG) cnt[t]=0;
  __syncthreads();
  for (int i=t;i<Nn;i+=256) atomicAdd(&cnt[batch[i]],1);
  __syncthreads();
  if (t==0){ int run=0; for (int g=0; g<GG; g++){ goff[g]=run; run+=cnt[g]; } goff[GG]=run; }
}
__global__ __launch_bounds__(256) void pool_accum(const float* __restrict__ H,
    const int* __restrict__ batch, float* __restrict__ psum){
  int d = blockIdx.y*256 + threadIdx.x;
  int n0 = blockIdx.x*32;
  int g = batch[n0];
  float s = 0.f;
  for (int k=0;k<32;k++){
    int n = n0+k;
    int gn = batch[n];
    if (gn != g){ atomicAdd(&psum[(size_t)g*FW+d], s); s=0.f; g=gn; }
    s += H[(size_t)n*FW + d];
  }
  atomicAdd(&psum[(size_t)g*FW+d], s);
}
__global__ __launch_bounds__(256) void final_out(const float* __restrict__ psum,
    const int* __restrict__ goff,
    const float* __restrict__ fc_w, const float* __restrict__ fc_b, float* __restrict__ out){
  int g = blockIdx.x; int t = threadIdx.x;
  float cinv = 0.25f / fmaxf((float)(goff[g+1]-goff[g]), 1.f);
  float p = 0.f;
  for (int d=t; d<HIDC; d+=256){
    float f = cinv*(psum[(size_t)g*FW+d] + psum[(size_t)g*FW+HIDC+d]
                  + psum[(size_t)g*FW+2*HIDC+d] + psum[(size_t)g*FW+3*HIDC+d]);
    p += f*fc_w[d];
  }
  __shared__ float red[4];
  for (int off=32; off; off>>=1) p += __shfl_down(p,off);
  if ((t&63)==0) red[t>>6]=p;
  __syncthreads();
  if (t==0) out[g] = red[0]+red[1]+red[2]+red[3] + fc_b[0];
}

extern "C" void kernel_launch(void* const* d_in, const int* in_sizes, int n_in,
                              void* d_out, int out_size, void* d_ws, size_t ws_size,
                              hipStream_t stream){
  const float* x      = (const float*)d_in[0];
  const int*   ei     = (const int*)d_in[1];
  const int*   batch  = (const int*)d_in[2];
  const float* W_gat  = (const float*)d_in[3];
  const float* a_src  = (const float*)d_in[4];
  const float* a_dst  = (const float*)d_in[5];
  const float* W_gcn  = (const float*)d_in[6];
  const float* fc_w   = (const float*)d_in[7];
  const float* fc_b   = (const float*)d_in[8];
  float* out = (float*)d_out;
  const int* src = ei;
  const int* dst = ei + Ee;

  char* w = (char*)d_ws;
  size_t off = 0;
  auto alloc = [&](size_t bytes)->char*{ char* p = w + off; off = (off + bytes + 255) & ~(size_t)255; return p; };
  float*  Hfeat  = (float*)alloc((size_t)Nn*FW*4);
  ushort* hbf    = (ushort*)alloc((size_t)Nn*FW*2);       // GAT projection; REUSED as Phi
  ushort* Hbf    = (ushort*)alloc((size_t)Nn*FW*2);
  ushort* Xbf    = (ushort*)alloc((size_t)Nn*INC*2);
  ushort* WgatT  = (ushort*)alloc((size_t)HEADS*INC*HIDC*2);
  ushort* WgcnT  = (ushort*)alloc((size_t)NLAY*HIDC*HIDC*2);
  float* lgs    = (float*)alloc((size_t)Nn*HEADS*4);
  float* lgd    = (float*)alloc((size_t)Nn*HEADS*4);
  // ---- contiguous zero-init region (single memset) ----
  int* indeg    = (int*)alloc(Nn*4);                      // 16 KB
  int* fill_d   = (int*)alloc(Nn*4);                      // 16 KB
  int* cnt_s    = (int*)alloc(Nn*4);                      // 16 KB
  int* fill_s   = (int*)alloc(Nn*4);                      // 16 KB
  float* psum   = (float*)alloc((size_t)GG*FW*4);         // 128 KB
  unsigned int* bitmap = (unsigned int*)alloc((size_t)Nn*Nn/8);  // 2 MB
  size_t zero_bytes = (size_t)Nn*4*4 + (size_t)GG*FW*4 + (size_t)Nn*Nn/8;
  // ---- rest ----
  int* rowptr_d = (int*)alloc((Nn+1)*4);
  int* slist    = (int*)alloc(Ee*4);
  int* rowptr_s = (int*)alloc((Nn+1)*4);
  int2* cwlist  = (int2*)alloc((size_t)Ee*8);
  int* flag     = (int*)alloc(Ee*4);
  float* dinv   = (float*)alloc(Nn*4);
  int* goff     = (int*)alloc((GG+1)*4);
  ushort* Phi   = hbf;

  hipMemsetAsync(indeg, 0, zero_bytes, stream);

  // ---- input prep ----
  tobf<<<(Nn*INC)/256,256,0,stream>>>(x, Xbf);
  tbf<<<dim3(16,16,HEADS),256,0,stream>>>(W_gat, WgatT);
  tbf<<<dim3(16,16,NLAY),256,0,stream>>>(W_gcn, WgcnT);

  // ---- GAT projection (bf16 MFMA, async staging) ----
  gemm_bf<<<dim3(FW/128, Nn/128),256,0,stream>>>(Xbf, WgatT,
      nullptr, nullptr, hbf, Nn, FW, INC, 0);
  compute_lg<<<Nn,256,0,stream>>>(hbf, a_src, a_dst, lgs, lgd);

  // ---- fused CSR build ----
  edge_pass1<<<Ee/256,256,0,stream>>>(src, dst, indeg, bitmap, cnt_s, flag);
  exscan2<<<2,1024,0,stream>>>(indeg, rowptr_d, cnt_s, rowptr_s);
  compute_dinv<<<Nn/256,256,0,stream>>>(cnt_s, dinv);
  edge_pass2<<<Ee/256,256,0,stream>>>(src, dst, flag, rowptr_d, fill_d, slist,
                                      rowptr_s, fill_s, cwlist, dinv);
  gat_aggregate<<<Nn,256,0,stream>>>(hbf, lgs, lgd, rowptr_d, slist, Hfeat, Hbf);

  // ---- residual GCN layers ----
  for (int l=0;l<NLAY;l++){
    spmm_bf<<<Nn,256,0,stream>>>(Hbf, Phi, rowptr_s, cwlist, dinv);
    gemm_bf<<<dim3(HIDC/128, (Nn*HEADS)/128),256,0,stream>>>(Phi,
        WgcnT + (size_t)l*HIDC*HIDC,
        Hfeat, Hfeat, (l==NLAY-1)? nullptr : Hbf, Nn*HEADS, HIDC, HIDC, 1);
  }

  // ---- pooling + FC ----
  graph_offsets<<<1,256,0,stream>>>(batch, goff);
  pool_accum<<<dim3(Nn/32, FW/256),256,0,stream>>>(Hfeat, batch, psum);
  final_out<<<GG,256,0,stream>>>(psum, goff, fc_w, fc_b, out);
}

// Round 8
// 432.434 us; speedup vs baseline: 1.0628x; 1.0628x over previous
//
#include <hip/hip_runtime.h>
#include <cstdint>
#include <cstddef>

#define Nn    4096
#define Ee    131072
#define INC   512
#define HIDC  512
#define HEADS 4
#define NLAY  3
#define GG    16
#define FW    2048   // HEADS*HIDC

typedef __attribute__((ext_vector_type(8))) short bfrag;   // 8 bf16 (4 VGPRs)
typedef __attribute__((ext_vector_type(4))) float ffrag;   // 4 fp32 acc
typedef __attribute__((ext_vector_type(4))) uint uint4v;
typedef __attribute__((ext_vector_type(4))) float float4v;

__device__ __forceinline__ ushort f2bf(float v){
  uint u = __builtin_bit_cast(uint, v);
  u += 0x7fffu + ((u>>16)&1u);          // RNE
  return (ushort)(u>>16);
}
__device__ __forceinline__ float bf2f(ushort s){
  uint u = ((uint)s)<<16; return __builtin_bit_cast(float, u);
}
// acc[0..7] += w * unpack8(bf16x8 in uint4)
__device__ __forceinline__ void fma8(float* acc, uint4 g, float w){
  uint u[4] = {g.x, g.y, g.z, g.w};
  #pragma unroll
  for (int q=0;q<4;q++){
    float lo = __builtin_bit_cast(float, u[q]<<16);
    float hi = __builtin_bit_cast(float, u[q] & 0xffff0000u);
    acc[2*q]   += w*lo;
    acc[2*q+1] += w*hi;
  }
}
__device__ __forceinline__ void nt_store_u4(void* p, uint a, uint b, uint c, uint d){
  uint4v x = {a,b,c,d};
  __builtin_nontemporal_store(x, (uint4v*)p);
}
__device__ __forceinline__ void nt_store_f4(void* p, float a, float b, float c, float d){
  float4v x = {a,b,c,d};
  __builtin_nontemporal_store(x, (float4v*)p);
}
__device__ __forceinline__ void nt_pack8(void* p, const float* a){
  nt_store_u4(p,
    (uint)f2bf(a[0]) | ((uint)f2bf(a[1])<<16),
    (uint)f2bf(a[2]) | ((uint)f2bf(a[3])<<16),
    (uint)f2bf(a[4]) | ((uint)f2bf(a[5])<<16),
    (uint)f2bf(a[6]) | ((uint)f2bf(a[7])<<16));
}

// ---------------- fp32 -> bf16 elementwise ----------------
__global__ __launch_bounds__(256) void tobf(const float* __restrict__ X, ushort* __restrict__ Xb){
  int i = blockIdx.x*256 + threadIdx.x;
  Xb[i] = f2bf(X[i]);
}

// ---------------- batched 512x512 transpose -> bf16: W[b][r][c] -> T[b][c][r] ----------------
__global__ __launch_bounds__(256) void tbf(const float* __restrict__ W, ushort* __restrict__ T){
  __shared__ float tile[32][33];
  int b = blockIdx.z;
  int r0 = blockIdx.y*32, c0 = blockIdx.x*32;
  int t = threadIdx.x;
  int i = t>>3, j0 = (t&7)*4;
  const float* Wb = W + (size_t)b*512*512;
  float4 v = *(const float4*)(Wb + (size_t)(r0+i)*512 + c0 + j0);
  tile[i][j0]=v.x; tile[i][j0+1]=v.y; tile[i][j0+2]=v.z; tile[i][j0+3]=v.w;
  __syncthreads();
  ushort* o = T + (size_t)b*512*512 + (size_t)(c0+i)*512 + r0 + j0;
  #pragma unroll
  for (int q=0;q<4;q++) o[q] = f2bf(tile[j0+q][i]);
}

// ---------------- bf16 MFMA GEMM: C = A@B^T, 128x128 tile ----------------
// Round-6 structure (measured good): register prefetch of next tile overlaps MFMA.
// LDS fragment-major [kquad][row][8 shorts]:
//   offset(row,k) = ((k>>3)*128 + row)*8 + (k&7)
// => every ds_read_b128 and staging write is the canonical lane*16B pattern.
__global__ __launch_bounds__(256) void gemm_bf(
    const ushort* __restrict__ A, const ushort* __restrict__ B,
    const float* __restrict__ Res, float* __restrict__ Cf, ushort* __restrict__ Cb,
    int M, int N, int K, int relu_res)
{
  __shared__ __align__(16) ushort Ah[4096];   // 128 rows x 32 k = 8 KB
  __shared__ __align__(16) ushort Bh[4096];
  int t = threadIdx.x;
  int m0 = blockIdx.y*128, n0 = blockIdx.x*128;
  int srow = t>>1, c = t&1, scol = c*16;       // stage: 2 threads/row, 16 shorts each
  int wave = t>>6, lane = t&63;
  int wm = (wave&1)*64, wn = (wave>>1)*64;
  int lm = lane&15, quad = lane>>4;

  ffrag acc[4][4];
  #pragma unroll
  for (int i=0;i<4;i++){
    #pragma unroll
    for (int j=0;j<4;j++) acc[i][j] = (ffrag){0.f,0.f,0.f,0.f};
  }

  const ushort* pA = A + (size_t)(m0+srow)*K + scol;
  const ushort* pB = B + (size_t)(n0+srow)*K + scol;

  uint4 ra0 = *(const uint4*)(pA);  uint4 ra1 = *(const uint4*)(pA+8);
  uint4 rb0 = *(const uint4*)(pB);  uint4 rb1 = *(const uint4*)(pB+8);

  int w0 = ((2*c)*128 + srow)*8;     // quad 2c  (shorts scol..scol+7)
  int w1 = w0 + 1024;                // quad 2c+1 (shorts scol+8..scol+15)
  for (int k0 = 0; k0 < K; k0 += 32){
    __syncthreads();
    *(uint4*)&Ah[w0] = ra0; *(uint4*)&Ah[w1] = ra1;
    *(uint4*)&Bh[w0] = rb0; *(uint4*)&Bh[w1] = rb1;
    __syncthreads();
    if (k0+32 < K){
      ra0 = *(const uint4*)(pA+k0+32); ra1 = *(const uint4*)(pA+k0+40);
      rb0 = *(const uint4*)(pB+k0+32); rb1 = *(const uint4*)(pB+k0+40);
    }
    bfrag af[4];
    #pragma unroll
    for (int mt=0; mt<4; mt++)
      af[mt] = *(const bfrag*)&Ah[(quad*128 + wm + mt*16 + lm)*8];
    #pragma unroll
    for (int nt=0; nt<4; nt++){
      bfrag bf = *(const bfrag*)&Bh[(quad*128 + wn + nt*16 + lm)*8];
      #pragma unroll
      for (int mt=0; mt<4; mt++)
        acc[mt][nt] = __builtin_amdgcn_mfma_f32_16x16x32_bf16(af[mt], bf, acc[mt][nt], 0,0,0);
    }
  }

  #pragma unroll
  for (int mt=0; mt<4; mt++){
    #pragma unroll
    for (int nt=0; nt<4; nt++){
      #pragma unroll
      for (int r=0;r<4;r++){
        int grow = m0 + wm + mt*16 + quad*4 + r;
        int gcol = n0 + wn + nt*16 + lm;
        size_t off = (size_t)grow*N + gcol;
        float v = acc[mt][nt][r];
        if (relu_res) v = fmaxf(v,0.f) + Res[off];
        if (Cf) __builtin_nontemporal_store(v, &Cf[off]);
        if (Cb) __builtin_nontemporal_store(f2bf(v), &Cb[off]);
      }
    }
  }
}

// ---------------- attention logits per (node,head) ----------------
__global__ __launch_bounds__(256) void compute_lg(const ushort* __restrict__ hbf,
    const float* __restrict__ a_src, const float* __restrict__ a_dst,
    float* __restrict__ lgs, float* __restrict__ lgd){
  int n = blockIdx.x; int t = threadIdx.x;
  int hd = t>>6, lane = t&63;
  uint4 g = *(const uint4*)(hbf + (size_t)n*FW + hd*HIDC + lane*8);
  float h[8] = {0,0,0,0,0,0,0,0};
  fma8(h, g, 1.0f);
  float4 as0 = *(const float4*)(a_src + hd*HIDC + lane*8);
  float4 as1 = *(const float4*)(a_src + hd*HIDC + lane*8 + 4);
  float4 ad0 = *(const float4*)(a_dst + hd*HIDC + lane*8);
  float4 ad1 = *(const float4*)(a_dst + hd*HIDC + lane*8 + 4);
  float s1 = h[0]*as0.x + h[1]*as0.y + h[2]*as0.z + h[3]*as0.w
           + h[4]*as1.x + h[5]*as1.y + h[6]*as1.z + h[7]*as1.w;
  float s2 = h[0]*ad0.x + h[1]*ad0.y + h[2]*ad0.z + h[3]*ad0.w
           + h[4]*ad1.x + h[5]*ad1.y + h[6]*ad1.z + h[7]*ad1.w;
  for (int off=32; off; off>>=1){ s1 += __shfl_down(s1,off); s2 += __shfl_down(s2,off); }
  if (lane==0){ lgs[n*HEADS+hd]=s1; lgd[n*HEADS+hd]=s2; }
}

// ---------------- fused edge pass 1: in-degree hist + set-semantics dedup ----------------
__global__ __launch_bounds__(256) void edge_pass1(const int* __restrict__ src, const int* __restrict__ dst,
    int* __restrict__ indeg, unsigned int* __restrict__ bitmap,
    int* __restrict__ cnt_s, int* __restrict__ flag){
  int e = blockIdx.x*256+threadIdx.x; if (e>=Ee) return;
  int s = src[e], d = dst[e];
  atomicAdd(&indeg[d],1);
  unsigned int key = (unsigned int)s*Nn + (unsigned int)d;
  unsigned int bit = 1u<<(key&31);
  unsigned int old = atomicOr(&bitmap[key>>5], bit);
  int f = (old & bit) ? 0 : 1;
  flag[e] = f;
  if (f) atomicAdd(&cnt_s[s],1);
}

// ---------------- dual exclusive scan ----------------
__global__ __launch_bounds__(1024) void exscan2(const int* __restrict__ cnt0, int* __restrict__ rp0,
    const int* __restrict__ cnt1, int* __restrict__ rp1){
  const int* cnt = blockIdx.x ? cnt1 : cnt0;
  int* rowptr    = blockIdx.x ? rp1  : rp0;
  __shared__ int sums[1024];
  int t = threadIdx.x;
  int v[4]; int s=0;
  #pragma unroll
  for (int i=0;i<4;i++){ int idx=t*4+i; v[i] = cnt[idx]; s+=v[i]; }
  sums[t]=s; __syncthreads();
  for (int off=1; off<1024; off<<=1){
    int other = (t>=off)? sums[t-off] : 0;
    __syncthreads();
    sums[t] += other;
    __syncthreads();
  }
  int run = (t>0)? sums[t-1] : 0;
  #pragma unroll
  for (int i=0;i<4;i++){ int idx=t*4+i; rowptr[idx]=run; run+=v[i]; }
  if (t==1023) rowptr[Nn]=sums[1023];
}

__global__ __launch_bounds__(256) void compute_dinv(const int* __restrict__ cnt, float* __restrict__ dinv){
  int n = blockIdx.x*256+threadIdx.x; if (n<Nn) dinv[n] = 1.0f/sqrtf((float)(1+cnt[n]));
}

// ---------------- fused edge pass 2: scatter dst-CSR (src vals) + src-CSR (col,dinv) ----------------
__global__ __launch_bounds__(256) void edge_pass2(const int* __restrict__ src, const int* __restrict__ dst,
    const int* __restrict__ flag,
    const int* __restrict__ rp_d, int* __restrict__ fill_d, int* __restrict__ slist,
    const int* __restrict__ rp_s, int* __restrict__ fill_s, int2* __restrict__ cw,
    const float* __restrict__ dinv){
  int e = blockIdx.x*256+threadIdx.x; if (e>=Ee) return;
  int s = src[e], d = dst[e];
  int p = atomicAdd(&fill_d[d],1); slist[rp_d[d]+p] = s;
  if (flag[e]){
    int q = atomicAdd(&fill_s[s],1);
    cw[rp_s[s]+q] = make_int2(d, __float_as_int(dinv[d]));
  }
}

// ---------------- GAT softmax-aggregate: block = (4 nodes) x (1 head), wave = node ----------------
__global__ __launch_bounds__(256) void gat_aggregate(const ushort* __restrict__ hbf,
    const float* __restrict__ lgs, const float* __restrict__ lgd,
    const int* __restrict__ rowptr, const int* __restrict__ slist,
    float* __restrict__ Hfeat, ushort* __restrict__ Hbf){
  int t = threadIdx.x;
  int wv = __builtin_amdgcn_readfirstlane(t>>6);
  int lane = t&63;
  int b = blockIdx.x;
  int hd = __builtin_amdgcn_readfirstlane(b & 3);
  int n = ((b>>2)<<2) + wv;
  int beg = rowptr[n], deg = rowptr[n+1]-beg;
  float ldst = lgd[n*HEADS+hd];
  // ---- single-pass online softmax (m,z) ----
  float m_ = -3.4e38f, z_ = 0.f;
  int   s0 = 0; float v0 = 0.f;
  for (int i=lane; i<deg; i+=64){
    int s = slist[beg+i];
    float v = lgs[s*HEADS+hd] + ldst;
    v = v>0.f ? v : 0.2f*v;
    if (i<64){ s0=s; v0=v; }
    float mn = fmaxf(m_, v);
    z_ = z_*__expf(m_-mn) + __expf(v-mn);
    m_ = mn;
  }
  for (int o=32;o;o>>=1){
    float mo = __shfl_down(m_,o), zo = __shfl_down(z_,o);
    float mn = fmaxf(m_, mo);
    z_ = z_*__expf(m_-mn) + zo*__expf(mo-mn);
    m_ = mn;
  }
  float mx = __shfl(m_,0);
  float zs = __shfl(z_,0);
  float inv = 1.f/(zs+1e-16f);
  // ---- weighted accumulate, 64-edge chunks, 8x-batched loads ----
  float acc[8] = {0,0,0,0,0,0,0,0};
  const ushort* hb = hbf + hd*HIDC + lane*8;
  for (int base=0; base<deg; base+=64){
    float al; int s;
    if (base==0){
      s = s0;
      al = (lane<deg) ? __expf(v0-mx)*inv : 0.f;
    } else {
      int i = base+lane;
      al = 0.f; s = 0;
      if (i<deg){
        s = slist[beg+i];
        float v = lgs[s*HEADS+hd] + ldst; v = v>0.f ? v : 0.2f*v;
        al = __expf(v-mx)*inv;
      }
    }
    int cn = min(64, deg-base);
    int c = 0;
    for (; c+8<=cn; c+=8){
      uint4 g[8]; float a[8];
      #pragma unroll
      for (int q=0;q<8;q++){
        a[q] = __shfl(al,c+q);
        int ss = __shfl(s,c+q);
        g[q] = *(const uint4*)(hb + (size_t)ss*FW);
      }
      #pragma unroll
      for (int q=0;q<8;q++) fma8(acc, g[q], a[q]);
    }
    for (; c+4<=cn; c+=4){
      uint4 g[4]; float a[4];
      #pragma unroll
      for (int q=0;q<4;q++){
        a[q] = __shfl(al,c+q);
        int ss = __shfl(s,c+q);
        g[q] = *(const uint4*)(hb + (size_t)ss*FW);
      }
      #pragma unroll
      for (int q=0;q<4;q++) fma8(acc, g[q], a[q]);
    }
    for (; c<cn; c++){
      float a = __shfl(al,c);
      int ss  = __shfl(s,c);
      uint4 g = *(const uint4*)(hb + (size_t)ss*FW);
      fma8(acc, g, a);
    }
  }
  size_t off = (size_t)n*FW + hd*HIDC + lane*8;
  nt_store_f4(Hfeat + off,     acc[0],acc[1],acc[2],acc[3]);
  nt_store_f4(Hfeat + off + 4, acc[4],acc[5],acc[6],acc[7]);
  nt_pack8(Hbf + off, acc);
}

// ---------------- SpMM: block = (4 nodes) x (1 chunk), chunk = blockIdx.x & 3 ----------------
__global__ __launch_bounds__(256) void spmm_bf(const ushort* __restrict__ Hbf,
    ushort* __restrict__ Phi,
    const int* __restrict__ rowptr, const int2* __restrict__ cw, const float* __restrict__ dinv){
  int t = threadIdx.x;
  int wv = __builtin_amdgcn_readfirstlane(t>>6);
  int lane = t&63;
  int b = blockIdx.x;
  int ck = __builtin_amdgcn_readfirstlane(b & 3);
  int n = ((b>>2)<<2) + wv;
  int f = (ck<<9) + lane*8;
  float di = dinv[n];
  float acc[8] = {0,0,0,0,0,0,0,0};
  const ushort* hb = Hbf + f;
  uint4 self = *(const uint4*)(hb + (size_t)n*FW);
  fma8(acc, self, di*di);
  int beg = rowptr[n], end = rowptr[n+1];
  for (int base=beg; base<end; base+=64){
    int i = base + lane;
    int m = n; float w = 0.f;
    if (i < end){ int2 e = cw[i]; m = e.x; w = di*__int_as_float(e.y); }
    int cn = min(64, end-base);
    int c = 0;
    for (; c+8<=cn; c+=8){
      uint4 g[8]; float ww[8];
      #pragma unroll
      for (int q=0;q<8;q++){
        ww[q] = __shfl(w,c+q);
        int mm = __shfl(m,c+q);
        g[q] = *(const uint4*)(hb + (size_t)mm*FW);
      }
      #pragma unroll
      for (int q=0;q<8;q++) fma8(acc, g[q], ww[q]);
    }
    for (; c+4<=cn; c+=4){
      uint4 g[4]; float ww[4];
      #pragma unroll
      for (int q=0;q<4;q++){
        ww[q] = __shfl(w,c+q);
        int mm = __shfl(m,c+q);
        g[q] = *(const uint4*)(hb + (size_t)mm*FW);
      }
      #pragma unroll
      for (int q=0;q<4;q++) fma8(acc, g[q], ww[q]);
    }
    for (; c<cn; c++){
      int mm   = __shfl(m,c);
      float ww = __shfl(w,c);
      uint4 g = *(const uint4*)(hb + (size_t)mm*FW);
      fma8(acc, g, ww);
    }
  }
  float a[8];
  #pragma unroll
  for (int q=0;q<8;q++) a[q]=acc[q];
  nt_pack8(Phi + (size_t)n*FW + f, a);
}

// ---------------- pooling ----------------
__global__ __launch_bounds__(256) void graph_offsets(const int* __restrict__ batch, int* __restrict__ goff){
  __shared__ int cnt[GG];
  int t = threadIdx.x;
  if (t<GG) cnt[t]=0;
  __syncthreads();
  for (int i=t;i<Nn;i+=256) atomicAdd(&cnt[batch[i]],1);
  __syncthreads();
  if (t==0){ int run=0; for (int g=0; g<GG; g++){ goff[g]=run; run+=cnt[g]; } goff[GG]=run; }
}
__global__ __launch_bounds__(256) void pool_accum(const float* __restrict__ H,
    const int* __restrict__ batch, float* __restrict__ psum){
  int d = blockIdx.y*256 + threadIdx.x;
  int n0 = blockIdx.x*32;
  int g = batch[n0];
  float s = 0.f;
  for (int k=0;k<32;k++){
    int n = n0+k;
    int gn = batch[n];
    if (gn != g){ atomicAdd(&psum[(size_t)g*FW+d], s); s=0.f; g=gn; }
    s += H[(size_t)n*FW + d];
  }
  atomicAdd(&psum[(size_t)g*FW+d], s);
}
__global__ __launch_bounds__(256) void final_out(const float* __restrict__ psum,
    const int* __restrict__ goff,
    const float* __restrict__ fc_w, const float* __restrict__ fc_b, float* __restrict__ out){
  int g = blockIdx.x; int t = threadIdx.x;
  float cinv = 0.25f / fmaxf((float)(goff[g+1]-goff[g]), 1.f);
  float p = 0.f;
  for (int d=t; d<HIDC; d+=256){
    float f = cinv*(psum[(size_t)g*FW+d] + psum[(size_t)g*FW+HIDC+d]
                  + psum[(size_t)g*FW+2*HIDC+d] + psum[(size_t)g*FW+3*HIDC+d]);
    p += f*fc_w[d];
  }
  __shared__ float red[4];
  for (int off=32; off; off>>=1) p += __shfl_down(p,off);
  if ((t&63)==0) red[t>>6]=p;
  __syncthreads();
  if (t==0) out[g] = red[0]+red[1]+red[2]+red[3] + fc_b[0];
}

extern "C" void kernel_launch(void* const* d_in, const int* in_sizes, int n_in,
                              void* d_out, int out_size, void* d_ws, size_t ws_size,
                              hipStream_t stream){
  const float* x      = (const float*)d_in[0];
  const int*   ei     = (const int*)d_in[1];
  const int*   batch  = (const int*)d_in[2];
  const float* W_gat  = (const float*)d_in[3];
  const float* a_src  = (const float*)d_in[4];
  const float* a_dst  = (const float*)d_in[5];
  const float* W_gcn  = (const float*)d_in[6];
  const float* fc_w   = (const float*)d_in[7];
  const float* fc_b   = (const float*)d_in[8];
  float* out = (float*)d_out;
  const int* src = ei;
  const int* dst = ei + Ee;

  char* w = (char*)d_ws;
  size_t off = 0;
  auto alloc = [&](size_t bytes)->char*{ char* p = w + off; off = (off + bytes + 255) & ~(size_t)255; return p; };
  float*  Hfeat  = (float*)alloc((size_t)Nn*FW*4);
  ushort* hbf    = (ushort*)alloc((size_t)Nn*FW*2);       // GAT projection; REUSED as Phi
  ushort* Hbf    = (ushort*)alloc((size_t)Nn*FW*2);
  ushort* Xbf    = (ushort*)alloc((size_t)Nn*INC*2);
  ushort* WgatT  = (ushort*)alloc((size_t)HEADS*INC*HIDC*2);
  ushort* WgcnT  = (ushort*)alloc((size_t)NLAY*HIDC*HIDC*2);
  float* lgs    = (float*)alloc((size_t)Nn*HEADS*4);
  float* lgd    = (float*)alloc((size_t)Nn*HEADS*4);
  // ---- contiguous zero-init region (single memset) ----
  int* indeg    = (int*)alloc(Nn*4);                      // 16 KB
  int* fill_d   = (int*)alloc(Nn*4);                      // 16 KB
  int* cnt_s    = (int*)alloc(Nn*4);                      // 16 KB
  int* fill_s   = (int*)alloc(Nn*4);                      // 16 KB
  float* psum   = (float*)alloc((size_t)GG*FW*4);         // 128 KB
  unsigned int* bitmap = (unsigned int*)alloc((size_t)Nn*Nn/8);  // 2 MB
  size_t zero_bytes = (size_t)Nn*4*4 + (size_t)GG*FW*4 + (size_t)Nn*Nn/8;
  // ---- rest ----
  int* rowptr_d = (int*)alloc((Nn+1)*4);
  int* slist    = (int*)alloc(Ee*4);
  int* rowptr_s = (int*)alloc((Nn+1)*4);
  int2* cwlist  = (int2*)alloc((size_t)Ee*8);
  int* flag     = (int*)alloc(Ee*4);
  float* dinv   = (float*)alloc(Nn*4);
  int* goff     = (int*)alloc((GG+1)*4);
  ushort* Phi   = hbf;

  hipMemsetAsync(indeg, 0, zero_bytes, stream);

  // ---- input prep ----
  tobf<<<(Nn*INC)/256,256,0,stream>>>(x, Xbf);
  tbf<<<dim3(16,16,HEADS),256,0,stream>>>(W_gat, WgatT);
  tbf<<<dim3(16,16,NLAY),256,0,stream>>>(W_gcn, WgcnT);

  // ---- GAT projection (bf16 MFMA) ----
  gemm_bf<<<dim3(FW/128, Nn/128),256,0,stream>>>(Xbf, WgatT,
      nullptr, nullptr, hbf, Nn, FW, INC, 0);
  compute_lg<<<Nn,256,0,stream>>>(hbf, a_src, a_dst, lgs, lgd);

  // ---- fused CSR build ----
  edge_pass1<<<Ee/256,256,0,stream>>>(src, dst, indeg, bitmap, cnt_s, flag);
  exscan2<<<2,1024,0,stream>>>(indeg, rowptr_d, cnt_s, rowptr_s);
  compute_dinv<<<Nn/256,256,0,stream>>>(cnt_s, dinv);
  edge_pass2<<<Ee/256,256,0,stream>>>(src, dst, flag, rowptr_d, fill_d, slist,
                                      rowptr_s, fill_s, cwlist, dinv);
  gat_aggregate<<<Nn,256,0,stream>>>(hbf, lgs, lgd, rowptr_d, slist, Hfeat, Hbf);

  // ---- residual GCN layers ----
  for (int l=0;l<NLAY;l++){
    spmm_bf<<<Nn,256,0,stream>>>(Hbf, Phi, rowptr_s, cwlist, dinv);
    gemm_bf<<<dim3(HIDC/128, (Nn*HEADS)/128),256,0,stream>>>(Phi,
        WgcnT + (size_t)l*HIDC*HIDC,
        Hfeat, Hfeat, (l==NLAY-1)? nullptr : Hbf, Nn*HEADS, HIDC, HIDC, 1);
  }

  // ---- pooling + FC ----
  graph_offsets<<<1,256,0,stream>>>(batch, goff);
  pool_accum<<<dim3(Nn/32, FW/256),256,0,stream>>>(Hfeat, batch, psum);
  final_out<<<GG,256,0,stream>>>(psum, goff, fc_w, fc_b, out);
}

// Round 9
// 420.077 us; speedup vs baseline: 1.0941x; 1.0294x over previous
//
#include <hip/hip_runtime.h>
#include <cstdint>
#include <cstddef>

#define Nn    4096
#define Ee    131072
#define INC   512
#define HIDC  512
#define HEADS 4
#define NLAY  3
#define GG    16
#define FW    2048   // HEADS*HIDC

typedef __attribute__((ext_vector_type(8))) short bfrag;   // 8 bf16 (4 VGPRs)
typedef __attribute__((ext_vector_type(4))) float ffrag;   // 4 fp32 acc

__device__ __forceinline__ ushort f2bf(float v){
  uint u = __builtin_bit_cast(uint, v);
  u += 0x7fffu + ((u>>16)&1u);          // RNE
  return (ushort)(u>>16);
}
__device__ __forceinline__ float bf2f(ushort s){
  uint u = ((uint)s)<<16; return __builtin_bit_cast(float, u);
}
// acc[0..7] += w * unpack8(bf16x8 in uint4)
__device__ __forceinline__ void fma8(float* acc, uint4 g, float w){
  uint u[4] = {g.x, g.y, g.z, g.w};
  #pragma unroll
  for (int q=0;q<4;q++){
    float lo = __builtin_bit_cast(float, u[q]<<16);
    float hi = __builtin_bit_cast(float, u[q] & 0xffff0000u);
    acc[2*q]   += w*lo;
    acc[2*q+1] += w*hi;
  }
}
__device__ __forceinline__ void pack8(void* p, const float* a){
  uint4 o;
  o.x = (uint)f2bf(a[0]) | ((uint)f2bf(a[1])<<16);
  o.y = (uint)f2bf(a[2]) | ((uint)f2bf(a[3])<<16);
  o.z = (uint)f2bf(a[4]) | ((uint)f2bf(a[5])<<16);
  o.w = (uint)f2bf(a[6]) | ((uint)f2bf(a[7])<<16);
  *(uint4*)p = o;
}

// ---------------- fp32 -> bf16 elementwise ----------------
__global__ __launch_bounds__(256) void tobf(const float* __restrict__ X, ushort* __restrict__ Xb){
  int i = blockIdx.x*256 + threadIdx.x;
  Xb[i] = f2bf(X[i]);
}

// ---------------- batched 512x512 transpose -> bf16: W[b][r][c] -> T[b][c][r] ----------------
__global__ __launch_bounds__(256) void tbf(const float* __restrict__ W, ushort* __restrict__ T){
  __shared__ float tile[32][33];
  int b = blockIdx.z;
  int r0 = blockIdx.y*32, c0 = blockIdx.x*32;
  int t = threadIdx.x;
  int i = t>>3, j0 = (t&7)*4;
  const float* Wb = W + (size_t)b*512*512;
  float4 v = *(const float4*)(Wb + (size_t)(r0+i)*512 + c0 + j0);
  tile[i][j0]=v.x; tile[i][j0+1]=v.y; tile[i][j0+2]=v.z; tile[i][j0+3]=v.w;
  __syncthreads();
  ushort* o = T + (size_t)b*512*512 + (size_t)(c0+i)*512 + r0 + j0;
  #pragma unroll
  for (int q=0;q<4;q++) o[q] = f2bf(tile[j0+q][i]);
}

// ---------------- bf16 MFMA GEMM: C = A@B^T, 128x128 tile, LDS double-buffer ----------------
// LDS fragment-major [kquad][row][8 shorts]; one barrier per K-iter (ping-pong),
// register prefetch issued one full iteration before its LDS write.
__global__ __launch_bounds__(256) void gemm_bf(
    const ushort* __restrict__ A, const ushort* __restrict__ B,
    const float* __restrict__ Res, float* __restrict__ Cf, ushort* __restrict__ Cb,
    int M, int N, int K, int relu_res)
{
  __shared__ __align__(16) ushort Ah[2][4096];   // 2 x 8 KB
  __shared__ __align__(16) ushort Bh[2][4096];
  int t = threadIdx.x;
  int m0 = blockIdx.y*128, n0 = blockIdx.x*128;
  int srow = t>>1, c = t&1, scol = c*16;         // stage: 2 threads/row, 16 shorts each
  int wave = t>>6, lane = t&63;
  int wm = (wave&1)*64, wn = (wave>>1)*64;
  int lm = lane&15, quad = lane>>4;

  ffrag acc[4][4];
  #pragma unroll
  for (int i=0;i<4;i++){
    #pragma unroll
    for (int j=0;j<4;j++) acc[i][j] = (ffrag){0.f,0.f,0.f,0.f};
  }

  const ushort* pA = A + (size_t)(m0+srow)*K + scol;
  const ushort* pB = B + (size_t)(n0+srow)*K + scol;

  int w0 = ((2*c)*128 + srow)*8;     // quad 2c
  int w1 = w0 + 1024;                // quad 2c+1

  // tile 0 -> regs -> buf0
  uint4 ra0 = *(const uint4*)(pA);  uint4 ra1 = *(const uint4*)(pA+8);
  uint4 rb0 = *(const uint4*)(pB);  uint4 rb1 = *(const uint4*)(pB+8);
  *(uint4*)&Ah[0][w0] = ra0; *(uint4*)&Ah[0][w1] = ra1;
  *(uint4*)&Bh[0][w0] = rb0; *(uint4*)&Bh[0][w1] = rb1;
  // prefetch tile 1
  if (K > 32){
    ra0 = *(const uint4*)(pA+32); ra1 = *(const uint4*)(pA+40);
    rb0 = *(const uint4*)(pB+32); rb1 = *(const uint4*)(pB+40);
  }
  __syncthreads();

  for (int k0 = 0; k0 < K; k0 += 32){
    int cur = (k0>>5)&1, nxt = cur^1;
    bfrag af[4];
    #pragma unroll
    for (int mt=0; mt<4; mt++)
      af[mt] = *(const bfrag*)&Ah[cur][(quad*128 + wm + mt*16 + lm)*8];
    #pragma unroll
    for (int nt=0; nt<4; nt++){
      bfrag bf = *(const bfrag*)&Bh[cur][(quad*128 + wn + nt*16 + lm)*8];
      #pragma unroll
      for (int mt=0; mt<4; mt++)
        acc[mt][nt] = __builtin_amdgcn_mfma_f32_16x16x32_bf16(af[mt], bf, acc[mt][nt], 0,0,0);
    }
    if (k0+32 < K){
      // write tile k+1 into the other buffer (vmcnt wait lands here, after MFMAs)
      *(uint4*)&Ah[nxt][w0] = ra0; *(uint4*)&Ah[nxt][w1] = ra1;
      *(uint4*)&Bh[nxt][w0] = rb0; *(uint4*)&Bh[nxt][w1] = rb1;
      if (k0+64 < K){
        ra0 = *(const uint4*)(pA+k0+64); ra1 = *(const uint4*)(pA+k0+72);
        rb0 = *(const uint4*)(pB+k0+64); rb1 = *(const uint4*)(pB+k0+72);
      }
    }
    __syncthreads();
  }

  #pragma unroll
  for (int mt=0; mt<4; mt++){
    #pragma unroll
    for (int nt=0; nt<4; nt++){
      #pragma unroll
      for (int r=0;r<4;r++){
        int grow = m0 + wm + mt*16 + quad*4 + r;
        int gcol = n0 + wn + nt*16 + lm;
        size_t off = (size_t)grow*N + gcol;
        float v = acc[mt][nt][r];
        if (relu_res) v = fmaxf(v,0.f) + Res[off];
        if (Cf) Cf[off] = v;
        if (Cb) Cb[off] = f2bf(v);
      }
    }
  }
}

// ---------------- attention logits per (node,head) ----------------
__global__ __launch_bounds__(256) void compute_lg(const ushort* __restrict__ hbf,
    const float* __restrict__ a_src, const float* __restrict__ a_dst,
    float* __restrict__ lgs, float* __restrict__ lgd){
  int n = blockIdx.x; int t = threadIdx.x;
  int hd = t>>6, lane = t&63;
  uint4 g = *(const uint4*)(hbf + (size_t)n*FW + hd*HIDC + lane*8);
  float h[8] = {0,0,0,0,0,0,0,0};
  fma8(h, g, 1.0f);
  float4 as0 = *(const float4*)(a_src + hd*HIDC + lane*8);
  float4 as1 = *(const float4*)(a_src + hd*HIDC + lane*8 + 4);
  float4 ad0 = *(const float4*)(a_dst + hd*HIDC + lane*8);
  float4 ad1 = *(const float4*)(a_dst + hd*HIDC + lane*8 + 4);
  float s1 = h[0]*as0.x + h[1]*as0.y + h[2]*as0.z + h[3]*as0.w
           + h[4]*as1.x + h[5]*as1.y + h[6]*as1.z + h[7]*as1.w;
  float s2 = h[0]*ad0.x + h[1]*ad0.y + h[2]*ad0.z + h[3]*ad0.w
           + h[4]*ad1.x + h[5]*ad1.y + h[6]*ad1.z + h[7]*ad1.w;
  for (int off=32; off; off>>=1){ s1 += __shfl_down(s1,off); s2 += __shfl_down(s2,off); }
  if (lane==0){ lgs[n*HEADS+hd]=s1; lgd[n*HEADS+hd]=s2; }
}

// ---------------- fused edge pass 1: in-degree hist + set-semantics dedup ----------------
__global__ __launch_bounds__(256) void edge_pass1(const int* __restrict__ src, const int* __restrict__ dst,
    int* __restrict__ indeg, unsigned int* __restrict__ bitmap,
    int* __restrict__ cnt_s, int* __restrict__ flag){
  int e = blockIdx.x*256+threadIdx.x; if (e>=Ee) return;
  int s = src[e], d = dst[e];
  atomicAdd(&indeg[d],1);
  unsigned int key = (unsigned int)s*Nn + (unsigned int)d;
  unsigned int bit = 1u<<(key&31);
  unsigned int old = atomicOr(&bitmap[key>>5], bit);
  int f = (old & bit) ? 0 : 1;
  flag[e] = f;
  if (f) atomicAdd(&cnt_s[s],1);
}

// ---------------- dual exclusive scan ----------------
__global__ __launch_bounds__(1024) void exscan2(const int* __restrict__ cnt0, int* __restrict__ rp0,
    const int* __restrict__ cnt1, int* __restrict__ rp1){
  const int* cnt = blockIdx.x ? cnt1 : cnt0;
  int* rowptr    = blockIdx.x ? rp1  : rp0;
  __shared__ int sums[1024];
  int t = threadIdx.x;
  int v[4]; int s=0;
  #pragma unroll
  for (int i=0;i<4;i++){ int idx=t*4+i; v[i] = cnt[idx]; s+=v[i]; }
  sums[t]=s; __syncthreads();
  for (int off=1; off<1024; off<<=1){
    int other = (t>=off)? sums[t-off] : 0;
    __syncthreads();
    sums[t] += other;
    __syncthreads();
  }
  int run = (t>0)? sums[t-1] : 0;
  #pragma unroll
  for (int i=0;i<4;i++){ int idx=t*4+i; rowptr[idx]=run; run+=v[i]; }
  if (t==1023) rowptr[Nn]=sums[1023];
}

__global__ __launch_bounds__(256) void compute_dinv(const int* __restrict__ cnt, float* __restrict__ dinv){
  int n = blockIdx.x*256+threadIdx.x; if (n<Nn) dinv[n] = 1.0f/sqrtf((float)(1+cnt[n]));
}

// ---------------- fused edge pass 2: scatter dst-CSR (src vals) + src-CSR (col,dinv) ----------------
__global__ __launch_bounds__(256) void edge_pass2(const int* __restrict__ src, const int* __restrict__ dst,
    const int* __restrict__ flag,
    const int* __restrict__ rp_d, int* __restrict__ fill_d, int* __restrict__ slist,
    const int* __restrict__ rp_s, int* __restrict__ fill_s, int2* __restrict__ cw,
    const float* __restrict__ dinv){
  int e = blockIdx.x*256+threadIdx.x; if (e>=Ee) return;
  int s = src[e], d = dst[e];
  int p = atomicAdd(&fill_d[d],1); slist[rp_d[d]+p] = s;
  if (flag[e]){
    int q = atomicAdd(&fill_s[s],1);
    cw[rp_s[s]+q] = make_int2(d, __float_as_int(dinv[d]));
  }
}

// ---------------- GAT softmax-aggregate: block = (4 nodes) x (1 head), wave = node ----------------
__global__ __launch_bounds__(256) void gat_aggregate(const ushort* __restrict__ hbf,
    const float* __restrict__ lgs, const float* __restrict__ lgd,
    const int* __restrict__ rowptr, const int* __restrict__ slist,
    float* __restrict__ Hfeat, ushort* __restrict__ Hbf){
  int t = threadIdx.x;
  int wv = __builtin_amdgcn_readfirstlane(t>>6);
  int lane = t&63;
  int b = blockIdx.x;
  int hd = __builtin_amdgcn_readfirstlane(b & 3);
  int n = ((b>>2)<<2) + wv;
  int beg = rowptr[n], deg = rowptr[n+1]-beg;
  float ldst = lgd[n*HEADS+hd];
  // ---- single-pass online softmax (m,z) ----
  float m_ = -3.4e38f, z_ = 0.f;
  int   s0 = 0; float v0 = 0.f;
  for (int i=lane; i<deg; i+=64){
    int s = slist[beg+i];
    float v = lgs[s*HEADS+hd] + ldst;
    v = v>0.f ? v : 0.2f*v;
    if (i<64){ s0=s; v0=v; }
    float mn = fmaxf(m_, v);
    z_ = z_*__expf(m_-mn) + __expf(v-mn);
    m_ = mn;
  }
  for (int o=32;o;o>>=1){
    float mo = __shfl_down(m_,o), zo = __shfl_down(z_,o);
    float mn = fmaxf(m_, mo);
    z_ = z_*__expf(m_-mn) + zo*__expf(mo-mn);
    m_ = mn;
  }
  float mx = __shfl(m_,0);
  float zs = __shfl(z_,0);
  float inv = 1.f/(zs+1e-16f);
  // ---- weighted accumulate, 64-edge chunks, 8x-batched loads ----
  float acc[8] = {0,0,0,0,0,0,0,0};
  const ushort* hb = hbf + hd*HIDC + lane*8;
  for (int base=0; base<deg; base+=64){
    float al; int s;
    if (base==0){
      s = s0;
      al = (lane<deg) ? __expf(v0-mx)*inv : 0.f;
    } else {
      int i = base+lane;
      al = 0.f; s = 0;
      if (i<deg){
        s = slist[beg+i];
        float v = lgs[s*HEADS+hd] + ldst; v = v>0.f ? v : 0.2f*v;
        al = __expf(v-mx)*inv;
      }
    }
    int cn = min(64, deg-base);
    int c = 0;
    for (; c+8<=cn; c+=8){
      uint4 g[8]; float a[8];
      #pragma unroll
      for (int q=0;q<8;q++){
        a[q] = __shfl(al,c+q);
        int ss = __shfl(s,c+q);
        g[q] = *(const uint4*)(hb + (size_t)ss*FW);
      }
      #pragma unroll
      for (int q=0;q<8;q++) fma8(acc, g[q], a[q]);
    }
    for (; c+4<=cn; c+=4){
      uint4 g[4]; float a[4];
      #pragma unroll
      for (int q=0;q<4;q++){
        a[q] = __shfl(al,c+q);
        int ss = __shfl(s,c+q);
        g[q] = *(const uint4*)(hb + (size_t)ss*FW);
      }
      #pragma unroll
      for (int q=0;q<4;q++) fma8(acc, g[q], a[q]);
    }
    for (; c<cn; c++){
      float a = __shfl(al,c);
      int ss  = __shfl(s,c);
      uint4 g = *(const uint4*)(hb + (size_t)ss*FW);
      fma8(acc, g, a);
    }
  }
  size_t off = (size_t)n*FW + hd*HIDC + lane*8;
  *(float4*)(Hfeat + off)     = make_float4(acc[0],acc[1],acc[2],acc[3]);
  *(float4*)(Hfeat + off + 4) = make_float4(acc[4],acc[5],acc[6],acc[7]);
  pack8(Hbf + off, acc);
}

// ---------------- SpMM: block = (4 nodes) x (1 chunk), chunk = blockIdx.x & 3 ----------------
__global__ __launch_bounds__(256) void spmm_bf(const ushort* __restrict__ Hbf,
    ushort* __restrict__ Phi,
    const int* __restrict__ rowptr, const int2* __restrict__ cw, const float* __restrict__ dinv){
  int t = threadIdx.x;
  int wv = __builtin_amdgcn_readfirstlane(t>>6);
  int lane = t&63;
  int b = blockIdx.x;
  int ck = __builtin_amdgcn_readfirstlane(b & 3);
  int n = ((b>>2)<<2) + wv;
  int f = (ck<<9) + lane*8;
  float di = dinv[n];
  float acc[8] = {0,0,0,0,0,0,0,0};
  const ushort* hb = Hbf + f;
  uint4 self = *(const uint4*)(hb + (size_t)n*FW);
  fma8(acc, self, di*di);
  int beg = rowptr[n], end = rowptr[n+1];
  for (int base=beg; base<end; base+=64){
    int i = base + lane;
    int m = n; float w = 0.f;
    if (i < end){ int2 e = cw[i]; m = e.x; w = di*__int_as_float(e.y); }
    int cn = min(64, end-base);
    int c = 0;
    for (; c+8<=cn; c+=8){
      uint4 g[8]; float ww[8];
      #pragma unroll
      for (int q=0;q<8;q++){
        ww[q] = __shfl(w,c+q);
        int mm = __shfl(m,c+q);
        g[q] = *(const uint4*)(hb + (size_t)mm*FW);
      }
      #pragma unroll
      for (int q=0;q<8;q++) fma8(acc, g[q], ww[q]);
    }
    for (; c+4<=cn; c+=4){
      uint4 g[4]; float ww[4];
      #pragma unroll
      for (int q=0;q<4;q++){
        ww[q] = __shfl(w,c+q);
        int mm = __shfl(m,c+q);
        g[q] = *(const uint4*)(hb + (size_t)mm*FW);
      }
      #pragma unroll
      for (int q=0;q<4;q++) fma8(acc, g[q], ww[q]);
    }
    for (; c<cn; c++){
      int mm   = __shfl(m,c);
      float ww = __shfl(w,c);
      uint4 g = *(const uint4*)(hb + (size_t)mm*FW);
      fma8(acc, g, ww);
    }
  }
  pack8(Phi + (size_t)n*FW + f, acc);
}

// ---------------- pooling ----------------
__global__ __launch_bounds__(256) void graph_offsets(const int* __restrict__ batch, int* __restrict__ goff){
  __shared__ int cnt[GG];
  int t = threadIdx.x;
  if (t<GG) cnt[t]=0;
  __syncthreads();
  for (int i=t;i<Nn;i+=256) atomicAdd(&cnt[batch[i]],1);
  __syncthreads();
  if (t==0){ int run=0; for (int g=0; g<GG; g++){ goff[g]=run; run+=cnt[g]; } goff[GG]=run; }
}
__global__ __launch_bounds__(256) void pool_accum(const float* __restrict__ H,
    const int* __restrict__ batch, float* __restrict__ psum){
  int d = blockIdx.y*256 + threadIdx.x;
  int n0 = blockIdx.x*32;
  int g = batch[n0];
  float s = 0.f;
  for (int k=0;k<32;k++){
    int n = n0+k;
    int gn = batch[n];
    if (gn != g){ atomicAdd(&psum[(size_t)g*FW+d], s); s=0.f; g=gn; }
    s += H[(size_t)n*FW + d];
  }
  atomicAdd(&psum[(size_t)g*FW+d], s);
}
__global__ __launch_bounds__(256) void final_out(const float* __restrict__ psum,
    const int* __restrict__ goff,
    const float* __restrict__ fc_w, const float* __restrict__ fc_b, float* __restrict__ out){
  int g = blockIdx.x; int t = threadIdx.x;
  float cinv = 0.25f / fmaxf((float)(goff[g+1]-goff[g]), 1.f);
  float p = 0.f;
  for (int d=t; d<HIDC; d+=256){
    float f = cinv*(psum[(size_t)g*FW+d] + psum[(size_t)g*FW+HIDC+d]
                  + psum[(size_t)g*FW+2*HIDC+d] + psum[(size_t)g*FW+3*HIDC+d]);
    p += f*fc_w[d];
  }
  __shared__ float red[4];
  for (int off=32; off; off>>=1) p += __shfl_down(p,off);
  if ((t&63)==0) red[t>>6]=p;
  __syncthreads();
  if (t==0) out[g] = red[0]+red[1]+red[2]+red[3] + fc_b[0];
}

extern "C" void kernel_launch(void* const* d_in, const int* in_sizes, int n_in,
                              void* d_out, int out_size, void* d_ws, size_t ws_size,
                              hipStream_t stream){
  const float* x      = (const float*)d_in[0];
  const int*   ei     = (const int*)d_in[1];
  const int*   batch  = (const int*)d_in[2];
  const float* W_gat  = (const float*)d_in[3];
  const float* a_src  = (const float*)d_in[4];
  const float* a_dst  = (const float*)d_in[5];
  const float* W_gcn  = (const float*)d_in[6];
  const float* fc_w   = (const float*)d_in[7];
  const float* fc_b   = (const float*)d_in[8];
  float* out = (float*)d_out;
  const int* src = ei;
  const int* dst = ei + Ee;

  char* w = (char*)d_ws;
  size_t off = 0;
  auto alloc = [&](size_t bytes)->char*{ char* p = w + off; off = (off + bytes + 255) & ~(size_t)255; return p; };
  float*  Hfeat  = (float*)alloc((size_t)Nn*FW*4);
  ushort* hbf    = (ushort*)alloc((size_t)Nn*FW*2);       // GAT projection; REUSED as Phi
  ushort* Hbf    = (ushort*)alloc((size_t)Nn*FW*2);
  ushort* Xbf    = (ushort*)alloc((size_t)Nn*INC*2);
  ushort* WgatT  = (ushort*)alloc((size_t)HEADS*INC*HIDC*2);
  ushort* WgcnT  = (ushort*)alloc((size_t)NLAY*HIDC*HIDC*2);
  float* lgs    = (float*)alloc((size_t)Nn*HEADS*4);
  float* lgd    = (float*)alloc((size_t)Nn*HEADS*4);
  // ---- contiguous zero-init region (single memset) ----
  int* indeg    = (int*)alloc(Nn*4);                      // 16 KB
  int* fill_d   = (int*)alloc(Nn*4);                      // 16 KB
  int* cnt_s    = (int*)alloc(Nn*4);                      // 16 KB
  int* fill_s   = (int*)alloc(Nn*4);                      // 16 KB
  float* psum   = (float*)alloc((size_t)GG*FW*4);         // 128 KB
  unsigned int* bitmap = (unsigned int*)alloc((size_t)Nn*Nn/8);  // 2 MB
  size_t zero_bytes = (size_t)Nn*4*4 + (size_t)GG*FW*4 + (size_t)Nn*Nn/8;
  // ---- rest ----
  int* rowptr_d = (int*)alloc((Nn+1)*4);
  int* slist    = (int*)alloc(Ee*4);
  int* rowptr_s = (int*)alloc((Nn+1)*4);
  int2* cwlist  = (int2*)alloc((size_t)Ee*8);
  int* flag     = (int*)alloc(Ee*4);
  float* dinv   = (float*)alloc(Nn*4);
  int* goff     = (int*)alloc((GG+1)*4);
  ushort* Phi   = hbf;

  hipMemsetAsync(indeg, 0, zero_bytes, stream);

  // ---- input prep ----
  tobf<<<(Nn*INC)/256,256,0,stream>>>(x, Xbf);
  tbf<<<dim3(16,16,HEADS),256,0,stream>>>(W_gat, WgatT);
  tbf<<<dim3(16,16,NLAY),256,0,stream>>>(W_gcn, WgcnT);

  // ---- GAT projection (bf16 MFMA) ----
  gemm_bf<<<dim3(FW/128, Nn/128),256,0,stream>>>(Xbf, WgatT,
      nullptr, nullptr, hbf, Nn, FW, INC, 0);
  compute_lg<<<Nn,256,0,stream>>>(hbf, a_src, a_dst, lgs, lgd);

  // ---- fused CSR build ----
  edge_pass1<<<Ee/256,256,0,stream>>>(src, dst, indeg, bitmap, cnt_s, flag);
  exscan2<<<2,1024,0,stream>>>(indeg, rowptr_d, cnt_s, rowptr_s);
  compute_dinv<<<Nn/256,256,0,stream>>>(cnt_s, dinv);
  edge_pass2<<<Ee/256,256,0,stream>>>(src, dst, flag, rowptr_d, fill_d, slist,
                                      rowptr_s, fill_s, cwlist, dinv);
  gat_aggregate<<<Nn,256,0,stream>>>(hbf, lgs, lgd, rowptr_d, slist, Hfeat, Hbf);

  // ---- residual GCN layers ----
  for (int l=0;l<NLAY;l++){
    spmm_bf<<<Nn,256,0,stream>>>(Hbf, Phi, rowptr_s, cwlist, dinv);
    gemm_bf<<<dim3(HIDC/128, (Nn*HEADS)/128),256,0,stream>>>(Phi,
        WgcnT + (size_t)l*HIDC*HIDC,
        Hfeat, Hfeat, (l==NLAY-1)? nullptr : Hbf, Nn*HEADS, HIDC, HIDC, 1);
  }

  // ---- pooling + FC ----
  graph_offsets<<<1,256,0,stream>>>(batch, goff);
  pool_accum<<<dim3(Nn/32, FW/256),256,0,stream>>>(Hfeat, batch, psum);
  final_out<<<GG,256,0,stream>>>(psum, goff, fc_w, fc_b, out);
}

// Round 10
// 396.200 us; speedup vs baseline: 1.1600x; 1.0603x over previous
//
#include <hip/hip_runtime.h>
#include <cstdint>
#include <cstddef>

#define Nn    4096
#define Ee    131072
#define INC   512
#define HIDC  512
#define HEADS 4
#define NLAY  3
#define GG    16
#define FW    2048   // HEADS*HIDC

typedef __attribute__((ext_vector_type(8))) short bfrag;   // 8 bf16 (4 VGPRs)
typedef __attribute__((ext_vector_type(4))) float ffrag;   // 4 fp32 acc

__device__ __forceinline__ ushort f2bf(float v){
  uint u = __builtin_bit_cast(uint, v);
  u += 0x7fffu + ((u>>16)&1u);          // RNE
  return (ushort)(u>>16);
}
__device__ __forceinline__ float bf2f(ushort s){
  uint u = ((uint)s)<<16; return __builtin_bit_cast(float, u);
}
// acc[0..7] += w * unpack8(bf16x8 in uint4)
__device__ __forceinline__ void fma8(float* acc, uint4 g, float w){
  uint u[4] = {g.x, g.y, g.z, g.w};
  #pragma unroll
  for (int q=0;q<4;q++){
    float lo = __builtin_bit_cast(float, u[q]<<16);
    float hi = __builtin_bit_cast(float, u[q] & 0xffff0000u);
    acc[2*q]   += w*lo;
    acc[2*q+1] += w*hi;
  }
}
__device__ __forceinline__ void pack8(void* p, const float* a){
  uint4 o;
  o.x = (uint)f2bf(a[0]) | ((uint)f2bf(a[1])<<16);
  o.y = (uint)f2bf(a[2]) | ((uint)f2bf(a[3])<<16);
  o.z = (uint)f2bf(a[4]) | ((uint)f2bf(a[5])<<16);
  o.w = (uint)f2bf(a[6]) | ((uint)f2bf(a[7])<<16);
  *(uint4*)p = o;
}

// ---------------- fp32 -> bf16 elementwise ----------------
__global__ __launch_bounds__(256) void tobf(const float* __restrict__ X, ushort* __restrict__ Xb){
  int i = blockIdx.x*256 + threadIdx.x;
  Xb[i] = f2bf(X[i]);
}

// ---------------- batched 512x512 transpose -> bf16: W[b][r][c] -> T[b][c][r] ----------------
__global__ __launch_bounds__(256) void tbf(const float* __restrict__ W, ushort* __restrict__ T){
  __shared__ float tile[32][33];
  int b = blockIdx.z;
  int r0 = blockIdx.y*32, c0 = blockIdx.x*32;
  int t = threadIdx.x;
  int i = t>>3, j0 = (t&7)*4;
  const float* Wb = W + (size_t)b*512*512;
  float4 v = *(const float4*)(Wb + (size_t)(r0+i)*512 + c0 + j0);
  tile[i][j0]=v.x; tile[i][j0+1]=v.y; tile[i][j0+2]=v.z; tile[i][j0+3]=v.w;
  __syncthreads();
  ushort* o = T + (size_t)b*512*512 + (size_t)(c0+i)*512 + r0 + j0;
  #pragma unroll
  for (int q=0;q<4;q++) o[q] = f2bf(tile[j0+q][i]);
}

// ---------------- bf16 MFMA GEMM: C = A@B^T, 64(M)x128(N) tile, LDS double-buffer ----------------
// 2x grid vs 128x128 => 4 blocks/CU (grid was the occupancy limiter).
// LDS fragment-major [kquad][row][8 shorts]; one barrier per K-iter (ping-pong).
__global__ __launch_bounds__(256) void gemm_bf(
    const ushort* __restrict__ A, const ushort* __restrict__ B,
    const float* __restrict__ Res, float* __restrict__ Cf, ushort* __restrict__ Cb,
    int M, int N, int K, int relu_res)
{
  __shared__ __align__(16) ushort Ah[2][2048];   // 64 rows x 32 k
  __shared__ __align__(16) ushort Bh[2][4096];   // 128 rows x 32 k
  int t = threadIdx.x;
  int m0 = blockIdx.y*64, n0 = blockIdx.x*128;
  // staging A: 4 threads/row, 8 shorts (one kquad) each
  int srA = t>>2, kqA = t&3;
  const ushort* pA = A + (size_t)(m0+srA)*K + kqA*8;
  int wA = (kqA*64 + srA)*8;
  // staging B: 2 threads/row, 16 shorts (kquads 2c,2c+1) each
  int srB = t>>1, cB = t&1;
  const ushort* pB = B + (size_t)(n0+srB)*K + cB*16;
  int wB0 = ((2*cB)*128 + srB)*8;
  int wB1 = wB0 + 1024;

  int wave = t>>6, lane = t&63;
  int wm = (wave&1)*32, wn = (wave>>1)*64;
  int lm = lane&15, quad = lane>>4;

  ffrag acc[2][4];
  #pragma unroll
  for (int i=0;i<2;i++){
    #pragma unroll
    for (int j=0;j<4;j++) acc[i][j] = (ffrag){0.f,0.f,0.f,0.f};
  }

  // tile 0 -> regs -> buf0
  uint4 ra  = *(const uint4*)(pA);
  uint4 rb0 = *(const uint4*)(pB);  uint4 rb1 = *(const uint4*)(pB+8);
  *(uint4*)&Ah[0][wA]  = ra;
  *(uint4*)&Bh[0][wB0] = rb0; *(uint4*)&Bh[0][wB1] = rb1;
  // prefetch tile 1
  if (K > 32){
    ra  = *(const uint4*)(pA+32);
    rb0 = *(const uint4*)(pB+32); rb1 = *(const uint4*)(pB+40);
  }
  __syncthreads();

  for (int k0 = 0; k0 < K; k0 += 32){
    int cur = (k0>>5)&1, nxt = cur^1;
    bfrag af[2];
    #pragma unroll
    for (int mt=0; mt<2; mt++)
      af[mt] = *(const bfrag*)&Ah[cur][(quad*64 + wm + mt*16 + lm)*8];
    #pragma unroll
    for (int nt=0; nt<4; nt++){
      bfrag bf = *(const bfrag*)&Bh[cur][(quad*128 + wn + nt*16 + lm)*8];
      #pragma unroll
      for (int mt=0; mt<2; mt++)
        acc[mt][nt] = __builtin_amdgcn_mfma_f32_16x16x32_bf16(af[mt], bf, acc[mt][nt], 0,0,0);
    }
    if (k0+32 < K){
      *(uint4*)&Ah[nxt][wA]  = ra;
      *(uint4*)&Bh[nxt][wB0] = rb0; *(uint4*)&Bh[nxt][wB1] = rb1;
      if (k0+64 < K){
        ra  = *(const uint4*)(pA+k0+64);
        rb0 = *(const uint4*)(pB+k0+64); rb1 = *(const uint4*)(pB+k0+72);
      }
    }
    __syncthreads();
  }

  #pragma unroll
  for (int mt=0; mt<2; mt++){
    #pragma unroll
    for (int nt=0; nt<4; nt++){
      #pragma unroll
      for (int r=0;r<4;r++){
        int grow = m0 + wm + mt*16 + quad*4 + r;
        int gcol = n0 + wn + nt*16 + lm;
        size_t off = (size_t)grow*N + gcol;
        float v = acc[mt][nt][r];
        if (relu_res) v = fmaxf(v,0.f) + Res[off];
        if (Cf) Cf[off] = v;
        if (Cb) Cb[off] = f2bf(v);
      }
    }
  }
}

// ---------------- attention logits per (node,head) ----------------
__global__ __launch_bounds__(256) void compute_lg(const ushort* __restrict__ hbf,
    const float* __restrict__ a_src, const float* __restrict__ a_dst,
    float* __restrict__ lgs, float* __restrict__ lgd){
  int n = blockIdx.x; int t = threadIdx.x;
  int hd = t>>6, lane = t&63;
  uint4 g = *(const uint4*)(hbf + (size_t)n*FW + hd*HIDC + lane*8);
  float h[8] = {0,0,0,0,0,0,0,0};
  fma8(h, g, 1.0f);
  float4 as0 = *(const float4*)(a_src + hd*HIDC + lane*8);
  float4 as1 = *(const float4*)(a_src + hd*HIDC + lane*8 + 4);
  float4 ad0 = *(const float4*)(a_dst + hd*HIDC + lane*8);
  float4 ad1 = *(const float4*)(a_dst + hd*HIDC + lane*8 + 4);
  float s1 = h[0]*as0.x + h[1]*as0.y + h[2]*as0.z + h[3]*as0.w
           + h[4]*as1.x + h[5]*as1.y + h[6]*as1.z + h[7]*as1.w;
  float s2 = h[0]*ad0.x + h[1]*ad0.y + h[2]*ad0.z + h[3]*ad0.w
           + h[4]*ad1.x + h[5]*ad1.y + h[6]*ad1.z + h[7]*ad1.w;
  for (int off=32; off; off>>=1){ s1 += __shfl_down(s1,off); s2 += __shfl_down(s2,off); }
  if (lane==0){ lgs[n*HEADS+hd]=s1; lgd[n*HEADS+hd]=s2; }
}

// ---------------- fused edge pass 1: in-degree hist + set-semantics dedup ----------------
__global__ __launch_bounds__(256) void edge_pass1(const int* __restrict__ src, const int* __restrict__ dst,
    int* __restrict__ indeg, unsigned int* __restrict__ bitmap,
    int* __restrict__ cnt_s, int* __restrict__ flag){
  int e = blockIdx.x*256+threadIdx.x; if (e>=Ee) return;
  int s = src[e], d = dst[e];
  atomicAdd(&indeg[d],1);
  unsigned int key = (unsigned int)s*Nn + (unsigned int)d;
  unsigned int bit = 1u<<(key&31);
  unsigned int old = atomicOr(&bitmap[key>>5], bit);
  int f = (old & bit) ? 0 : 1;
  flag[e] = f;
  if (f) atomicAdd(&cnt_s[s],1);
}

// ---------------- dual exclusive scan ----------------
__global__ __launch_bounds__(1024) void exscan2(const int* __restrict__ cnt0, int* __restrict__ rp0,
    const int* __restrict__ cnt1, int* __restrict__ rp1){
  const int* cnt = blockIdx.x ? cnt1 : cnt0;
  int* rowptr    = blockIdx.x ? rp1  : rp0;
  __shared__ int sums[1024];
  int t = threadIdx.x;
  int v[4]; int s=0;
  #pragma unroll
  for (int i=0;i<4;i++){ int idx=t*4+i; v[i] = cnt[idx]; s+=v[i]; }
  sums[t]=s; __syncthreads();
  for (int off=1; off<1024; off<<=1){
    int other = (t>=off)? sums[t-off] : 0;
    __syncthreads();
    sums[t] += other;
    __syncthreads();
  }
  int run = (t>0)? sums[t-1] : 0;
  #pragma unroll
  for (int i=0;i<4;i++){ int idx=t*4+i; rowptr[idx]=run; run+=v[i]; }
  if (t==1023) rowptr[Nn]=sums[1023];
}

__global__ __launch_bounds__(256) void compute_dinv(const int* __restrict__ cnt, float* __restrict__ dinv){
  int n = blockIdx.x*256+threadIdx.x; if (n<Nn) dinv[n] = 1.0f/sqrtf((float)(1+cnt[n]));
}

// ---------------- fused edge pass 2: scatter dst-CSR (src vals) + src-CSR (col,dinv) ----------------
__global__ __launch_bounds__(256) void edge_pass2(const int* __restrict__ src, const int* __restrict__ dst,
    const int* __restrict__ flag,
    const int* __restrict__ rp_d, int* __restrict__ fill_d, int* __restrict__ slist,
    const int* __restrict__ rp_s, int* __restrict__ fill_s, int2* __restrict__ cw,
    const float* __restrict__ dinv){
  int e = blockIdx.x*256+threadIdx.x; if (e>=Ee) return;
  int s = src[e], d = dst[e];
  int p = atomicAdd(&fill_d[d],1); slist[rp_d[d]+p] = s;
  if (flag[e]){
    int q = atomicAdd(&fill_s[s],1);
    cw[rp_s[s]+q] = make_int2(d, __float_as_int(dinv[d]));
  }
}

// ---------------- GAT softmax-aggregate: block = (4 nodes) x (1 head), wave = node ----------------
__global__ __launch_bounds__(256) void gat_aggregate(const ushort* __restrict__ hbf,
    const float* __restrict__ lgs, const float* __restrict__ lgd,
    const int* __restrict__ rowptr, const int* __restrict__ slist,
    float* __restrict__ Hfeat, ushort* __restrict__ Hbf){
  int t = threadIdx.x;
  int wv = __builtin_amdgcn_readfirstlane(t>>6);
  int lane = t&63;
  int b = blockIdx.x;
  int hd = __builtin_amdgcn_readfirstlane(b & 3);
  int n = ((b>>2)<<2) + wv;
  int beg = rowptr[n], deg = rowptr[n+1]-beg;
  float ldst = lgd[n*HEADS+hd];
  // ---- single-pass online softmax (m,z) ----
  float m_ = -3.4e38f, z_ = 0.f;
  int   s0 = 0; float v0 = 0.f;
  for (int i=lane; i<deg; i+=64){
    int s = slist[beg+i];
    float v = lgs[s*HEADS+hd] + ldst;
    v = v>0.f ? v : 0.2f*v;
    if (i<64){ s0=s; v0=v; }
    float mn = fmaxf(m_, v);
    z_ = z_*__expf(m_-mn) + __expf(v-mn);
    m_ = mn;
  }
  for (int o=32;o;o>>=1){
    float mo = __shfl_down(m_,o), zo = __shfl_down(z_,o);
    float mn = fmaxf(m_, mo);
    z_ = z_*__expf(m_-mn) + zo*__expf(mo-mn);
    m_ = mn;
  }
  float mx = __shfl(m_,0);
  float zs = __shfl(z_,0);
  float inv = 1.f/(zs+1e-16f);
  // ---- weighted accumulate, 64-edge chunks, 8x-batched loads ----
  float acc[8] = {0,0,0,0,0,0,0,0};
  const ushort* hb = hbf + hd*HIDC + lane*8;
  for (int base=0; base<deg; base+=64){
    float al; int s;
    if (base==0){
      s = s0;
      al = (lane<deg) ? __expf(v0-mx)*inv : 0.f;
    } else {
      int i = base+lane;
      al = 0.f; s = 0;
      if (i<deg){
        s = slist[beg+i];
        float v = lgs[s*HEADS+hd] + ldst; v = v>0.f ? v : 0.2f*v;
        al = __expf(v-mx)*inv;
      }
    }
    int cn = min(64, deg-base);
    int c = 0;
    for (; c+8<=cn; c+=8){
      uint4 g[8]; float a[8];
      #pragma unroll
      for (int q=0;q<8;q++){
        a[q] = __shfl(al,c+q);
        int ss = __shfl(s,c+q);
        g[q] = *(const uint4*)(hb + (size_t)ss*FW);
      }
      #pragma unroll
      for (int q=0;q<8;q++) fma8(acc, g[q], a[q]);
    }
    for (; c+4<=cn; c+=4){
      uint4 g[4]; float a[4];
      #pragma unroll
      for (int q=0;q<4;q++){
        a[q] = __shfl(al,c+q);
        int ss = __shfl(s,c+q);
        g[q] = *(const uint4*)(hb + (size_t)ss*FW);
      }
      #pragma unroll
      for (int q=0;q<4;q++) fma8(acc, g[q], a[q]);
    }
    for (; c<cn; c++){
      float a = __shfl(al,c);
      int ss  = __shfl(s,c);
      uint4 g = *(const uint4*)(hb + (size_t)ss*FW);
      fma8(acc, g, a);
    }
  }
  size_t off = (size_t)n*FW + hd*HIDC + lane*8;
  *(float4*)(Hfeat + off)     = make_float4(acc[0],acc[1],acc[2],acc[3]);
  *(float4*)(Hfeat + off + 4) = make_float4(acc[4],acc[5],acc[6],acc[7]);
  pack8(Hbf + off, acc);
}

// ---------------- SpMM: block = (4 nodes) x (1 chunk), chunk = blockIdx.x & 3 ----------------
__global__ __launch_bounds__(256) void spmm_bf(const ushort* __restrict__ Hbf,
    ushort* __restrict__ Phi,
    const int* __restrict__ rowptr, const int2* __restrict__ cw, const float* __restrict__ dinv){
  int t = threadIdx.x;
  int wv = __builtin_amdgcn_readfirstlane(t>>6);
  int lane = t&63;
  int b = blockIdx.x;
  int ck = __builtin_amdgcn_readfirstlane(b & 3);
  int n = ((b>>2)<<2) + wv;
  int f = (ck<<9) + lane*8;
  float di = dinv[n];
  float acc[8] = {0,0,0,0,0,0,0,0};
  const ushort* hb = Hbf + f;
  uint4 self = *(const uint4*)(hb + (size_t)n*FW);
  fma8(acc, self, di*di);
  int beg = rowptr[n], end = rowptr[n+1];
  for (int base=beg; base<end; base+=64){
    int i = base + lane;
    int m = n; float w = 0.f;
    if (i < end){ int2 e = cw[i]; m = e.x; w = di*__int_as_float(e.y); }
    int cn = min(64, end-base);
    int c = 0;
    for (; c+8<=cn; c+=8){
      uint4 g[8]; float ww[8];
      #pragma unroll
      for (int q=0;q<8;q++){
        ww[q] = __shfl(w,c+q);
        int mm = __shfl(m,c+q);
        g[q] = *(const uint4*)(hb + (size_t)mm*FW);
      }
      #pragma unroll
      for (int q=0;q<8;q++) fma8(acc, g[q], ww[q]);
    }
    for (; c+4<=cn; c+=4){
      uint4 g[4]; float ww[4];
      #pragma unroll
      for (int q=0;q<4;q++){
        ww[q] = __shfl(w,c+q);
        int mm = __shfl(m,c+q);
        g[q] = *(const uint4*)(hb + (size_t)mm*FW);
      }
      #pragma unroll
      for (int q=0;q<4;q++) fma8(acc, g[q], ww[q]);
    }
    for (; c<cn; c++){
      int mm   = __shfl(m,c);
      float ww = __shfl(w,c);
      uint4 g = *(const uint4*)(hb + (size_t)mm*FW);
      fma8(acc, g, ww);
    }
  }
  pack8(Phi + (size_t)n*FW + f, acc);
}

// ---------------- pooling ----------------
__global__ __launch_bounds__(256) void graph_offsets(const int* __restrict__ batch, int* __restrict__ goff){
  __shared__ int cnt[GG];
  int t = threadIdx.x;
  if (t<GG) cnt[t]=0;
  __syncthreads();
  for (int i=t;i<Nn;i+=256) atomicAdd(&cnt[batch[i]],1);
  __syncthreads();
  if (t==0){ int run=0; for (int g=0; g<GG; g++){ goff[g]=run; run+=cnt[g]; } goff[GG]=run; }
}
__global__ __launch_bounds__(256) void pool_accum(const float* __restrict__ H,
    const int* __restrict__ batch, float* __restrict__ psum){
  int d = blockIdx.y*256 + threadIdx.x;
  int n0 = blockIdx.x*32;
  int g = batch[n0];
  float s = 0.f;
  for (int k=0;k<32;k++){
    int n = n0+k;
    int gn = batch[n];
    if (gn != g){ atomicAdd(&psum[(size_t)g*FW+d], s); s=0.f; g=gn; }
    s += H[(size_t)n*FW + d];
  }
  atomicAdd(&psum[(size_t)g*FW+d], s);
}
__global__ __launch_bounds__(256) void final_out(const float* __restrict__ psum,
    const int* __restrict__ goff,
    const float* __restrict__ fc_w, const float* __restrict__ fc_b, float* __restrict__ out){
  int g = blockIdx.x; int t = threadIdx.x;
  float cinv = 0.25f / fmaxf((float)(goff[g+1]-goff[g]), 1.f);
  float p = 0.f;
  for (int d=t; d<HIDC; d+=256){
    float f = cinv*(psum[(size_t)g*FW+d] + psum[(size_t)g*FW+HIDC+d]
                  + psum[(size_t)g*FW+2*HIDC+d] + psum[(size_t)g*FW+3*HIDC+d]);
    p += f*fc_w[d];
  }
  __shared__ float red[4];
  for (int off=32; off; off>>=1) p += __shfl_down(p,off);
  if ((t&63)==0) red[t>>6]=p;
  __syncthreads();
  if (t==0) out[g] = red[0]+red[1]+red[2]+red[3] + fc_b[0];
}

extern "C" void kernel_launch(void* const* d_in, const int* in_sizes, int n_in,
                              void* d_out, int out_size, void* d_ws, size_t ws_size,
                              hipStream_t stream){
  const float* x      = (const float*)d_in[0];
  const int*   ei     = (const int*)d_in[1];
  const int*   batch  = (const int*)d_in[2];
  const float* W_gat  = (const float*)d_in[3];
  const float* a_src  = (const float*)d_in[4];
  const float* a_dst  = (const float*)d_in[5];
  const float* W_gcn  = (const float*)d_in[6];
  const float* fc_w   = (const float*)d_in[7];
  const float* fc_b   = (const float*)d_in[8];
  float* out = (float*)d_out;
  const int* src = ei;
  const int* dst = ei + Ee;

  char* w = (char*)d_ws;
  size_t off = 0;
  auto alloc = [&](size_t bytes)->char*{ char* p = w + off; off = (off + bytes + 255) & ~(size_t)255; return p; };
  float*  Hfeat  = (float*)alloc((size_t)Nn*FW*4);
  ushort* hbf    = (ushort*)alloc((size_t)Nn*FW*2);       // GAT projection; REUSED as Phi
  ushort* Hbf    = (ushort*)alloc((size_t)Nn*FW*2);
  ushort* Xbf    = (ushort*)alloc((size_t)Nn*INC*2);
  ushort* WgatT  = (ushort*)alloc((size_t)HEADS*INC*HIDC*2);
  ushort* WgcnT  = (ushort*)alloc((size_t)NLAY*HIDC*HIDC*2);
  float* lgs    = (float*)alloc((size_t)Nn*HEADS*4);
  float* lgd    = (float*)alloc((size_t)Nn*HEADS*4);
  // ---- contiguous zero-init region (single memset) ----
  int* indeg    = (int*)alloc(Nn*4);                      // 16 KB
  int* fill_d   = (int*)alloc(Nn*4);                      // 16 KB
  int* cnt_s    = (int*)alloc(Nn*4);                      // 16 KB
  int* fill_s   = (int*)alloc(Nn*4);                      // 16 KB
  float* psum   = (float*)alloc((size_t)GG*FW*4);         // 128 KB
  unsigned int* bitmap = (unsigned int*)alloc((size_t)Nn*Nn/8);  // 2 MB
  size_t zero_bytes = (size_t)Nn*4*4 + (size_t)GG*FW*4 + (size_t)Nn*Nn/8;
  // ---- rest ----
  int* rowptr_d = (int*)alloc((Nn+1)*4);
  int* slist    = (int*)alloc(Ee*4);
  int* rowptr_s = (int*)alloc((Nn+1)*4);
  int2* cwlist  = (int2*)alloc((size_t)Ee*8);
  int* flag     = (int*)alloc(Ee*4);
  float* dinv   = (float*)alloc(Nn*4);
  int* goff     = (int*)alloc((GG+1)*4);
  ushort* Phi   = hbf;

  hipMemsetAsync(indeg, 0, zero_bytes, stream);

  // ---- input prep ----
  tobf<<<(Nn*INC)/256,256,0,stream>>>(x, Xbf);
  tbf<<<dim3(16,16,HEADS),256,0,stream>>>(W_gat, WgatT);
  tbf<<<dim3(16,16,NLAY),256,0,stream>>>(W_gcn, WgcnT);

  // ---- GAT projection (bf16 MFMA) ----
  gemm_bf<<<dim3(FW/128, Nn/64),256,0,stream>>>(Xbf, WgatT,
      nullptr, nullptr, hbf, Nn, FW, INC, 0);
  compute_lg<<<Nn,256,0,stream>>>(hbf, a_src, a_dst, lgs, lgd);

  // ---- fused CSR build ----
  edge_pass1<<<Ee/256,256,0,stream>>>(src, dst, indeg, bitmap, cnt_s, flag);
  exscan2<<<2,1024,0,stream>>>(indeg, rowptr_d, cnt_s, rowptr_s);
  compute_dinv<<<Nn/256,256,0,stream>>>(cnt_s, dinv);
  edge_pass2<<<Ee/256,256,0,stream>>>(src, dst, flag, rowptr_d, fill_d, slist,
                                      rowptr_s, fill_s, cwlist, dinv);
  gat_aggregate<<<Nn,256,0,stream>>>(hbf, lgs, lgd, rowptr_d, slist, Hfeat, Hbf);

  // ---- residual GCN layers ----
  for (int l=0;l<NLAY;l++){
    spmm_bf<<<Nn,256,0,stream>>>(Hbf, Phi, rowptr_s, cwlist, dinv);
    gemm_bf<<<dim3(HIDC/128, (Nn*HEADS)/64),256,0,stream>>>(Phi,
        WgcnT + (size_t)l*HIDC*HIDC,
        Hfeat, Hfeat, (l==NLAY-1)? nullptr : Hbf, Nn*HEADS, HIDC, HIDC, 1);
  }

  // ---- pooling + FC ----
  graph_offsets<<<1,256,0,stream>>>(batch, goff);
  pool_accum<<<dim3(Nn/32, FW/256),256,0,stream>>>(Hfeat, batch, psum);
  final_out<<<GG,256,0,stream>>>(psum, goff, fc_w, fc_b, out);
}

// Round 11
// 379.593 us; speedup vs baseline: 1.2107x; 1.0437x over previous
//
#include <hip/hip_runtime.h>
#include <cstdint>
#include <cstddef>

#define Nn    4096
#define Ee    131072
#define INC   512
#define HIDC  512
#define HEADS 4
#define NLAY  3
#define GG    16
#define FW    2048   // HEADS*HIDC

typedef __attribute__((ext_vector_type(8))) short bfrag;   // 8 bf16 (4 VGPRs)
typedef __attribute__((ext_vector_type(4))) float ffrag;   // 4 fp32 acc

__device__ __forceinline__ ushort f2bf(float v){
  uint u = __builtin_bit_cast(uint, v);
  u += 0x7fffu + ((u>>16)&1u);          // RNE
  return (ushort)(u>>16);
}
__device__ __forceinline__ float bf2f(ushort s){
  uint u = ((uint)s)<<16; return __builtin_bit_cast(float, u);
}
// acc[0..7] += w * unpack8(bf16x8 in uint4)
__device__ __forceinline__ void fma8(float* acc, uint4 g, float w){
  uint u[4] = {g.x, g.y, g.z, g.w};
  #pragma unroll
  for (int q=0;q<4;q++){
    float lo = __builtin_bit_cast(float, u[q]<<16);
    float hi = __builtin_bit_cast(float, u[q] & 0xffff0000u);
    acc[2*q]   += w*lo;
    acc[2*q+1] += w*hi;
  }
}
__device__ __forceinline__ void pack8(void* p, const float* a){
  uint4 o;
  o.x = (uint)f2bf(a[0]) | ((uint)f2bf(a[1])<<16);
  o.y = (uint)f2bf(a[2]) | ((uint)f2bf(a[3])<<16);
  o.z = (uint)f2bf(a[4]) | ((uint)f2bf(a[5])<<16);
  o.w = (uint)f2bf(a[6]) | ((uint)f2bf(a[7])<<16);
  *(uint4*)p = o;
}

// ---------------- fp32 -> bf16 elementwise ----------------
__global__ __launch_bounds__(256) void tobf(const float* __restrict__ X, ushort* __restrict__ Xb){
  int i = blockIdx.x*256 + threadIdx.x;
  Xb[i] = f2bf(X[i]);
}

// ---------------- batched 512x512 transpose -> bf16: W[b][r][c] -> T[b][c][r] ----------------
__global__ __launch_bounds__(256) void tbf(const float* __restrict__ W, ushort* __restrict__ T){
  __shared__ float tile[32][33];
  int b = blockIdx.z;
  int r0 = blockIdx.y*32, c0 = blockIdx.x*32;
  int t = threadIdx.x;
  int i = t>>3, j0 = (t&7)*4;
  const float* Wb = W + (size_t)b*512*512;
  float4 v = *(const float4*)(Wb + (size_t)(r0+i)*512 + c0 + j0);
  tile[i][j0]=v.x; tile[i][j0+1]=v.y; tile[i][j0+2]=v.z; tile[i][j0+3]=v.w;
  __syncthreads();
  ushort* o = T + (size_t)b*512*512 + (size_t)(c0+i)*512 + r0 + j0;
  #pragma unroll
  for (int q=0;q<4;q++) o[q] = f2bf(tile[j0+q][i]);
}

// ---------------- bf16 MFMA GEMM: C = A@B^T, 64(M)x128(N) tile, LDS double-buffer ----------------
// bf16 residual path: Res (bf16, optional) read, Cb (bf16) written — may alias elementwise.
__global__ __launch_bounds__(256) void gemm_bf(
    const ushort* __restrict__ A, const ushort* __restrict__ B,
    const ushort* Res, ushort* Cb,
    int M, int N, int K, int relu_res)
{
  __shared__ __align__(16) ushort Ah[2][2048];   // 64 rows x 32 k
  __shared__ __align__(16) ushort Bh[2][4096];   // 128 rows x 32 k
  int t = threadIdx.x;
  int m0 = blockIdx.y*64, n0 = blockIdx.x*128;
  // staging A: 4 threads/row, 8 shorts (one kquad) each
  int srA = t>>2, kqA = t&3;
  const ushort* pA = A + (size_t)(m0+srA)*K + kqA*8;
  int wA = (kqA*64 + srA)*8;
  // staging B: 2 threads/row, 16 shorts (kquads 2c,2c+1) each
  int srB = t>>1, cB = t&1;
  const ushort* pB = B + (size_t)(n0+srB)*K + cB*16;
  int wB0 = ((2*cB)*128 + srB)*8;
  int wB1 = wB0 + 1024;

  int wave = t>>6, lane = t&63;
  int wm = (wave&1)*32, wn = (wave>>1)*64;
  int lm = lane&15, quad = lane>>4;

  ffrag acc[2][4];
  #pragma unroll
  for (int i=0;i<2;i++){
    #pragma unroll
    for (int j=0;j<4;j++) acc[i][j] = (ffrag){0.f,0.f,0.f,0.f};
  }

  // tile 0 -> regs -> buf0
  uint4 ra  = *(const uint4*)(pA);
  uint4 rb0 = *(const uint4*)(pB);  uint4 rb1 = *(const uint4*)(pB+8);
  *(uint4*)&Ah[0][wA]  = ra;
  *(uint4*)&Bh[0][wB0] = rb0; *(uint4*)&Bh[0][wB1] = rb1;
  // prefetch tile 1
  if (K > 32){
    ra  = *(const uint4*)(pA+32);
    rb0 = *(const uint4*)(pB+32); rb1 = *(const uint4*)(pB+40);
  }
  __syncthreads();

  for (int k0 = 0; k0 < K; k0 += 32){
    int cur = (k0>>5)&1, nxt = cur^1;
    bfrag af[2];
    #pragma unroll
    for (int mt=0; mt<2; mt++)
      af[mt] = *(const bfrag*)&Ah[cur][(quad*64 + wm + mt*16 + lm)*8];
    #pragma unroll
    for (int nt=0; nt<4; nt++){
      bfrag bf = *(const bfrag*)&Bh[cur][(quad*128 + wn + nt*16 + lm)*8];
      #pragma unroll
      for (int mt=0; mt<2; mt++)
        acc[mt][nt] = __builtin_amdgcn_mfma_f32_16x16x32_bf16(af[mt], bf, acc[mt][nt], 0,0,0);
    }
    if (k0+32 < K){
      *(uint4*)&Ah[nxt][wA]  = ra;
      *(uint4*)&Bh[nxt][wB0] = rb0; *(uint4*)&Bh[nxt][wB1] = rb1;
      if (k0+64 < K){
        ra  = *(const uint4*)(pA+k0+64);
        rb0 = *(const uint4*)(pB+k0+64); rb1 = *(const uint4*)(pB+k0+72);
      }
    }
    __syncthreads();
  }

  #pragma unroll
  for (int mt=0; mt<2; mt++){
    #pragma unroll
    for (int nt=0; nt<4; nt++){
      #pragma unroll
      for (int r=0;r<4;r++){
        int grow = m0 + wm + mt*16 + quad*4 + r;
        int gcol = n0 + wn + nt*16 + lm;
        size_t off = (size_t)grow*N + gcol;
        float v = acc[mt][nt][r];
        if (relu_res) v = fmaxf(v,0.f) + bf2f(Res[off]);
        Cb[off] = f2bf(v);
      }
    }
  }
}

// ---------------- attention logits per (node,head) ----------------
__global__ __launch_bounds__(256) void compute_lg(const ushort* __restrict__ hbf,
    const float* __restrict__ a_src, const float* __restrict__ a_dst,
    float* __restrict__ lgs, float* __restrict__ lgd){
  int n = blockIdx.x; int t = threadIdx.x;
  int hd = t>>6, lane = t&63;
  uint4 g = *(const uint4*)(hbf + (size_t)n*FW + hd*HIDC + lane*8);
  float h[8] = {0,0,0,0,0,0,0,0};
  fma8(h, g, 1.0f);
  float4 as0 = *(const float4*)(a_src + hd*HIDC + lane*8);
  float4 as1 = *(const float4*)(a_src + hd*HIDC + lane*8 + 4);
  float4 ad0 = *(const float4*)(a_dst + hd*HIDC + lane*8);
  float4 ad1 = *(const float4*)(a_dst + hd*HIDC + lane*8 + 4);
  float s1 = h[0]*as0.x + h[1]*as0.y + h[2]*as0.z + h[3]*as0.w
           + h[4]*as1.x + h[5]*as1.y + h[6]*as1.z + h[7]*as1.w;
  float s2 = h[0]*ad0.x + h[1]*ad0.y + h[2]*ad0.z + h[3]*ad0.w
           + h[4]*ad1.x + h[5]*ad1.y + h[6]*ad1.z + h[7]*ad1.w;
  for (int off=32; off; off>>=1){ s1 += __shfl_down(s1,off); s2 += __shfl_down(s2,off); }
  if (lane==0){ lgs[n*HEADS+hd]=s1; lgd[n*HEADS+hd]=s2; }
}

// ---------------- fused edge pass 1: in-degree hist + set-semantics dedup ----------------
__global__ __launch_bounds__(256) void edge_pass1(const int* __restrict__ src, const int* __restrict__ dst,
    int* __restrict__ indeg, unsigned int* __restrict__ bitmap,
    int* __restrict__ cnt_s, int* __restrict__ flag){
  int e = blockIdx.x*256+threadIdx.x; if (e>=Ee) return;
  int s = src[e], d = dst[e];
  atomicAdd(&indeg[d],1);
  unsigned int key = (unsigned int)s*Nn + (unsigned int)d;
  unsigned int bit = 1u<<(key&31);
  unsigned int old = atomicOr(&bitmap[key>>5], bit);
  int f = (old & bit) ? 0 : 1;
  flag[e] = f;
  if (f) atomicAdd(&cnt_s[s],1);
}

// ---------------- dual exclusive scan ----------------
__global__ __launch_bounds__(1024) void exscan2(const int* __restrict__ cnt0, int* __restrict__ rp0,
    const int* __restrict__ cnt1, int* __restrict__ rp1){
  const int* cnt = blockIdx.x ? cnt1 : cnt0;
  int* rowptr    = blockIdx.x ? rp1  : rp0;
  __shared__ int sums[1024];
  int t = threadIdx.x;
  int v[4]; int s=0;
  #pragma unroll
  for (int i=0;i<4;i++){ int idx=t*4+i; v[i] = cnt[idx]; s+=v[i]; }
  sums[t]=s; __syncthreads();
  for (int off=1; off<1024; off<<=1){
    int other = (t>=off)? sums[t-off] : 0;
    __syncthreads();
    sums[t] += other;
    __syncthreads();
  }
  int run = (t>0)? sums[t-1] : 0;
  #pragma unroll
  for (int i=0;i<4;i++){ int idx=t*4+i; rowptr[idx]=run; run+=v[i]; }
  if (t==1023) rowptr[Nn]=sums[1023];
}

__global__ __launch_bounds__(256) void compute_dinv(const int* __restrict__ cnt, float* __restrict__ dinv){
  int n = blockIdx.x*256+threadIdx.x; if (n<Nn) dinv[n] = 1.0f/sqrtf((float)(1+cnt[n]));
}

// ---------------- fused edge pass 2: scatter dst-CSR (src vals) + src-CSR (col,dinv) ----------------
__global__ __launch_bounds__(256) void edge_pass2(const int* __restrict__ src, const int* __restrict__ dst,
    const int* __restrict__ flag,
    const int* __restrict__ rp_d, int* __restrict__ fill_d, int* __restrict__ slist,
    const int* __restrict__ rp_s, int* __restrict__ fill_s, int2* __restrict__ cw,
    const float* __restrict__ dinv){
  int e = blockIdx.x*256+threadIdx.x; if (e>=Ee) return;
  int s = src[e], d = dst[e];
  int p = atomicAdd(&fill_d[d],1); slist[rp_d[d]+p] = s;
  if (flag[e]){
    int q = atomicAdd(&fill_s[s],1);
    cw[rp_s[s]+q] = make_int2(d, __float_as_int(dinv[d]));
  }
}

// ---------------- GAT softmax-aggregate: block = (4 nodes) x (1 head), wave = node ----------------
__global__ __launch_bounds__(256) void gat_aggregate(const ushort* __restrict__ hbf,
    const float* __restrict__ lgs, const float* __restrict__ lgd,
    const int* __restrict__ rowptr, const int* __restrict__ slist,
    ushort* __restrict__ Hbf){
  int t = threadIdx.x;
  int wv = __builtin_amdgcn_readfirstlane(t>>6);
  int lane = t&63;
  int b = blockIdx.x;
  int hd = __builtin_amdgcn_readfirstlane(b & 3);
  int n = ((b>>2)<<2) + wv;
  int beg = rowptr[n], deg = rowptr[n+1]-beg;
  float ldst = lgd[n*HEADS+hd];
  // ---- single-pass online softmax (m,z) ----
  float m_ = -3.4e38f, z_ = 0.f;
  int   s0 = 0; float v0 = 0.f;
  for (int i=lane; i<deg; i+=64){
    int s = slist[beg+i];
    float v = lgs[s*HEADS+hd] + ldst;
    v = v>0.f ? v : 0.2f*v;
    if (i<64){ s0=s; v0=v; }
    float mn = fmaxf(m_, v);
    z_ = z_*__expf(m_-mn) + __expf(v-mn);
    m_ = mn;
  }
  for (int o=32;o;o>>=1){
    float mo = __shfl_down(m_,o), zo = __shfl_down(z_,o);
    float mn = fmaxf(m_, mo);
    z_ = z_*__expf(m_-mn) + zo*__expf(mo-mn);
    m_ = mn;
  }
  float mx = __shfl(m_,0);
  float zs = __shfl(z_,0);
  float inv = 1.f/(zs+1e-16f);
  // ---- weighted accumulate, 64-edge chunks, 8x-batched loads ----
  float acc[8] = {0,0,0,0,0,0,0,0};
  const ushort* hb = hbf + hd*HIDC + lane*8;
  for (int base=0; base<deg; base+=64){
    float al; int s;
    if (base==0){
      s = s0;
      al = (lane<deg) ? __expf(v0-mx)*inv : 0.f;
    } else {
      int i = base+lane;
      al = 0.f; s = 0;
      if (i<deg){
        s = slist[beg+i];
        float v = lgs[s*HEADS+hd] + ldst; v = v>0.f ? v : 0.2f*v;
        al = __expf(v-mx)*inv;
      }
    }
    int cn = min(64, deg-base);
    int c = 0;
    for (; c+8<=cn; c+=8){
      uint4 g[8]; float a[8];
      #pragma unroll
      for (int q=0;q<8;q++){
        a[q] = __shfl(al,c+q);
        int ss = __shfl(s,c+q);
        g[q] = *(const uint4*)(hb + (size_t)ss*FW);
      }
      #pragma unroll
      for (int q=0;q<8;q++) fma8(acc, g[q], a[q]);
    }
    for (; c+4<=cn; c+=4){
      uint4 g[4]; float a[4];
      #pragma unroll
      for (int q=0;q<4;q++){
        a[q] = __shfl(al,c+q);
        int ss = __shfl(s,c+q);
        g[q] = *(const uint4*)(hb + (size_t)ss*FW);
      }
      #pragma unroll
      for (int q=0;q<4;q++) fma8(acc, g[q], a[q]);
    }
    for (; c<cn; c++){
      float a = __shfl(al,c);
      int ss  = __shfl(s,c);
      uint4 g = *(const uint4*)(hb + (size_t)ss*FW);
      fma8(acc, g, a);
    }
  }
  size_t off = (size_t)n*FW + hd*HIDC + lane*8;
  pack8(Hbf + off, acc);
}

// ---------------- SpMM: block = (4 nodes) x (1 chunk), chunk = blockIdx.x & 3 ----------------
__global__ __launch_bounds__(256) void spmm_bf(const ushort* __restrict__ Hbf,
    ushort* __restrict__ Phi,
    const int* __restrict__ rowptr, const int2* __restrict__ cw, const float* __restrict__ dinv){
  int t = threadIdx.x;
  int wv = __builtin_amdgcn_readfirstlane(t>>6);
  int lane = t&63;
  int b = blockIdx.x;
  int ck = __builtin_amdgcn_readfirstlane(b & 3);
  int n = ((b>>2)<<2) + wv;
  int f = (ck<<9) + lane*8;
  float di = dinv[n];
  float acc[8] = {0,0,0,0,0,0,0,0};
  const ushort* hb = Hbf + f;
  uint4 self = *(const uint4*)(hb + (size_t)n*FW);
  fma8(acc, self, di*di);
  int beg = rowptr[n], end = rowptr[n+1];
  for (int base=beg; base<end; base+=64){
    int i = base + lane;
    int m = n; float w = 0.f;
    if (i < end){ int2 e = cw[i]; m = e.x; w = di*__int_as_float(e.y); }
    int cn = min(64, end-base);
    int c = 0;
    for (; c+8<=cn; c+=8){
      uint4 g[8]; float ww[8];
      #pragma unroll
      for (int q=0;q<8;q++){
        ww[q] = __shfl(w,c+q);
        int mm = __shfl(m,c+q);
        g[q] = *(const uint4*)(hb + (size_t)mm*FW);
      }
      #pragma unroll
      for (int q=0;q<8;q++) fma8(acc, g[q], ww[q]);
    }
    for (; c+4<=cn; c+=4){
      uint4 g[4]; float ww[4];
      #pragma unroll
      for (int q=0;q<4;q++){
        ww[q] = __shfl(w,c+q);
        int mm = __shfl(m,c+q);
        g[q] = *(const uint4*)(hb + (size_t)mm*FW);
      }
      #pragma unroll
      for (int q=0;q<4;q++) fma8(acc, g[q], ww[q]);
    }
    for (; c<cn; c++){
      int mm   = __shfl(m,c);
      float ww = __shfl(w,c);
      uint4 g = *(const uint4*)(hb + (size_t)mm*FW);
      fma8(acc, g, ww);
    }
  }
  pack8(Phi + (size_t)n*FW + f, acc);
}

// ---------------- pooling ----------------
__global__ __launch_bounds__(256) void graph_offsets(const int* __restrict__ batch, int* __restrict__ goff){
  __shared__ int cnt[GG];
  int t = threadIdx.x;
  if (t<GG) cnt[t]=0;
  __syncthreads();
  for (int i=t;i<Nn;i+=256) atomicAdd(&cnt[batch[i]],1);
  __syncthreads();
  if (t==0){ int run=0; for (int g=0; g<GG; g++){ goff[g]=run; run+=cnt[g]; } goff[GG]=run; }
}
// segmented sum of bf16 H into psum[G][FW] via atomics; batch is sorted
__global__ __launch_bounds__(256) void pool_accum(const ushort* __restrict__ Hb,
    const int* __restrict__ batch, float* __restrict__ psum){
  int d2 = blockIdx.y*256 + threadIdx.x;   // feature-pair index, FW/2 = 1024
  int n0 = blockIdx.x*32;
  int g = batch[n0];
  float s0 = 0.f, s1 = 0.f;
  for (int k=0;k<32;k++){
    int n = n0+k;
    int gn = batch[n];
    if (gn != g){
      atomicAdd(&psum[(size_t)g*FW + d2*2],   s0);
      atomicAdd(&psum[(size_t)g*FW + d2*2+1], s1);
      s0=0.f; s1=0.f; g=gn;
    }
    uint v = *(const uint*)(Hb + (size_t)n*FW + d2*2);
    s0 += bf2f((ushort)(v&0xffff));
    s1 += bf2f((ushort)(v>>16));
  }
  atomicAdd(&psum[(size_t)g*FW + d2*2],   s0);
  atomicAdd(&psum[(size_t)g*FW + d2*2+1], s1);
}
__global__ __launch_bounds__(256) void final_out(const float* __restrict__ psum,
    const int* __restrict__ goff,
    const float* __restrict__ fc_w, const float* __restrict__ fc_b, float* __restrict__ out){
  int g = blockIdx.x; int t = threadIdx.x;
  float cinv = 0.25f / fmaxf((float)(goff[g+1]-goff[g]), 1.f);
  float p = 0.f;
  for (int d=t; d<HIDC; d+=256){
    float f = cinv*(psum[(size_t)g*FW+d] + psum[(size_t)g*FW+HIDC+d]
                  + psum[(size_t)g*FW+2*HIDC+d] + psum[(size_t)g*FW+3*HIDC+d]);
    p += f*fc_w[d];
  }
  __shared__ float red[4];
  for (int off=32; off; off>>=1) p += __shfl_down(p,off);
  if ((t&63)==0) red[t>>6]=p;
  __syncthreads();
  if (t==0) out[g] = red[0]+red[1]+red[2]+red[3] + fc_b[0];
}

extern "C" void kernel_launch(void* const* d_in, const int* in_sizes, int n_in,
                              void* d_out, int out_size, void* d_ws, size_t ws_size,
                              hipStream_t stream){
  const float* x      = (const float*)d_in[0];
  const int*   ei     = (const int*)d_in[1];
  const int*   batch  = (const int*)d_in[2];
  const float* W_gat  = (const float*)d_in[3];
  const float* a_src  = (const float*)d_in[4];
  const float* a_dst  = (const float*)d_in[5];
  const float* W_gcn  = (const float*)d_in[6];
  const float* fc_w   = (const float*)d_in[7];
  const float* fc_b   = (const float*)d_in[8];
  float* out = (float*)d_out;
  const int* src = ei;
  const int* dst = ei + Ee;

  char* w = (char*)d_ws;
  size_t off = 0;
  auto alloc = [&](size_t bytes)->char*{ char* p = w + off; off = (off + bytes + 255) & ~(size_t)255; return p; };
  ushort* hbf    = (ushort*)alloc((size_t)Nn*FW*2);       // GAT projection; REUSED as Phi
  ushort* Hbf    = (ushort*)alloc((size_t)Nn*FW*2);       // bf16 node features H (residual trunk)
  ushort* Xbf    = (ushort*)alloc((size_t)Nn*INC*2);
  ushort* WgatT  = (ushort*)alloc((size_t)HEADS*INC*HIDC*2);
  ushort* WgcnT  = (ushort*)alloc((size_t)NLAY*HIDC*HIDC*2);
  float* lgs    = (float*)alloc((size_t)Nn*HEADS*4);
  float* lgd    = (float*)alloc((size_t)Nn*HEADS*4);
  // ---- contiguous zero-init region (single memset) ----
  int* indeg    = (int*)alloc(Nn*4);                      // 16 KB
  int* fill_d   = (int*)alloc(Nn*4);                      // 16 KB
  int* cnt_s    = (int*)alloc(Nn*4);                      // 16 KB
  int* fill_s   = (int*)alloc(Nn*4);                      // 16 KB
  float* psum   = (float*)alloc((size_t)GG*FW*4);         // 128 KB
  unsigned int* bitmap = (unsigned int*)alloc((size_t)Nn*Nn/8);  // 2 MB
  size_t zero_bytes = (size_t)Nn*4*4 + (size_t)GG*FW*4 + (size_t)Nn*Nn/8;
  // ---- rest ----
  int* rowptr_d = (int*)alloc((Nn+1)*4);
  int* slist    = (int*)alloc(Ee*4);
  int* rowptr_s = (int*)alloc((Nn+1)*4);
  int2* cwlist  = (int2*)alloc((size_t)Ee*8);
  int* flag     = (int*)alloc(Ee*4);
  float* dinv   = (float*)alloc(Nn*4);
  int* goff     = (int*)alloc((GG+1)*4);
  ushort* Phi   = hbf;

  hipMemsetAsync(indeg, 0, zero_bytes, stream);

  // ---- input prep ----
  tobf<<<(Nn*INC)/256,256,0,stream>>>(x, Xbf);
  tbf<<<dim3(16,16,HEADS),256,0,stream>>>(W_gat, WgatT);
  tbf<<<dim3(16,16,NLAY),256,0,stream>>>(W_gcn, WgcnT);

  // ---- GAT projection (bf16 MFMA) ----
  gemm_bf<<<dim3(FW/128, Nn/64),256,0,stream>>>(Xbf, WgatT,
      nullptr, hbf, Nn, FW, INC, 0);
  compute_lg<<<Nn,256,0,stream>>>(hbf, a_src, a_dst, lgs, lgd);

  // ---- fused CSR build ----
  edge_pass1<<<Ee/256,256,0,stream>>>(src, dst, indeg, bitmap, cnt_s, flag);
  exscan2<<<2,1024,0,stream>>>(indeg, rowptr_d, cnt_s, rowptr_s);
  compute_dinv<<<Nn/256,256,0,stream>>>(cnt_s, dinv);
  edge_pass2<<<Ee/256,256,0,stream>>>(src, dst, flag, rowptr_d, fill_d, slist,
                                      rowptr_s, fill_s, cwlist, dinv);
  gat_aggregate<<<Nn,256,0,stream>>>(hbf, lgs, lgd, rowptr_d, slist, Hbf);

  // ---- residual GCN layers (bf16 trunk) ----
  for (int l=0;l<NLAY;l++){
    spmm_bf<<<Nn,256,0,stream>>>(Hbf, Phi, rowptr_s, cwlist, dinv);
    gemm_bf<<<dim3(HIDC/128, (Nn*HEADS)/64),256,0,stream>>>(Phi,
        WgcnT + (size_t)l*HIDC*HIDC,
        Hbf, Hbf, Nn*HEADS, HIDC, HIDC, 1);
  }

  // ---- pooling + FC ----
  graph_offsets<<<1,256,0,stream>>>(batch, goff);
  pool_accum<<<dim3(Nn/32, FW/512),256,0,stream>>>(Hbf, batch, psum);
  final_out<<<GG,256,0,stream>>>(psum, goff, fc_w, fc_b, out);
}

// Round 12
// 370.393 us; speedup vs baseline: 1.2408x; 1.0248x over previous
//
#include <hip/hip_runtime.h>
#include <cstdint>
#include <cstddef>

#define Nn    4096
#define Ee    131072
#define INC   512
#define HIDC  512
#define HEADS 4
#define NLAY  3
#define GG    16
#define FW    2048   // HEADS*HIDC

typedef __attribute__((ext_vector_type(8))) short bfrag;   // 8 bf16 (4 VGPRs)
typedef __attribute__((ext_vector_type(4))) float ffrag;   // 4 fp32 acc

__device__ __forceinline__ ushort f2bf(float v){
  uint u = __builtin_bit_cast(uint, v);
  u += 0x7fffu + ((u>>16)&1u);          // RNE
  return (ushort)(u>>16);
}
__device__ __forceinline__ float bf2f(ushort s){
  uint u = ((uint)s)<<16; return __builtin_bit_cast(float, u);
}
// acc[0..7] += w * unpack8(bf16x8 in uint4)
__device__ __forceinline__ void fma8(float* acc, uint4 g, float w){
  uint u[4] = {g.x, g.y, g.z, g.w};
  #pragma unroll
  for (int q=0;q<4;q++){
    float lo = __builtin_bit_cast(float, u[q]<<16);
    float hi = __builtin_bit_cast(float, u[q] & 0xffff0000u);
    acc[2*q]   += w*lo;
    acc[2*q+1] += w*hi;
  }
}
__device__ __forceinline__ void pack8(void* p, const float* a){
  uint4 o;
  o.x = (uint)f2bf(a[0]) | ((uint)f2bf(a[1])<<16);
  o.y = (uint)f2bf(a[2]) | ((uint)f2bf(a[3])<<16);
  o.z = (uint)f2bf(a[4]) | ((uint)f2bf(a[5])<<16);
  o.w = (uint)f2bf(a[6]) | ((uint)f2bf(a[7])<<16);
  *(uint4*)p = o;
}

// ---------------- fused prep: x->bf16 | W transposes->bf16 | edge pass 1 ----------------
// blocks [0,8192): tobf; [8192,9984): tbf (7 z-slices: 4 gat + 3 gcn); [9984,10496): edge_pass1
__global__ __launch_bounds__(256) void prep(
    const float* __restrict__ x, ushort* __restrict__ Xb,
    const float* __restrict__ Wgat, ushort* __restrict__ Tgat,
    const float* __restrict__ Wgcn, ushort* __restrict__ Tgcn,
    const int* __restrict__ src, const int* __restrict__ dst,
    int* __restrict__ indeg, unsigned int* __restrict__ bitmap,
    int* __restrict__ cnt_s, int* __restrict__ flag){
  __shared__ float tile[32][33];
  int b = blockIdx.x, t = threadIdx.x;
  if (b < 8192){
    int i = b*256 + t;
    Xb[i] = f2bf(x[i]);
  } else if (b < 9984){
    int idx = b - 8192;
    int z = idx >> 8, xy = idx & 255;
    const float* W; ushort* T; int bb;
    if (z < 4){ W = Wgat; T = Tgat; bb = z; } else { W = Wgcn; T = Tgcn; bb = z-4; }
    int r0 = (xy>>4)*32, c0 = (xy&15)*32;
    int i = t>>3, j0 = (t&7)*4;
    const float* Wb = W + (size_t)bb*512*512;
    float4 v = *(const float4*)(Wb + (size_t)(r0+i)*512 + c0 + j0);
    tile[i][j0]=v.x; tile[i][j0+1]=v.y; tile[i][j0+2]=v.z; tile[i][j0+3]=v.w;
    __syncthreads();
    ushort* o = T + (size_t)bb*512*512 + (size_t)(c0+i)*512 + r0 + j0;
    #pragma unroll
    for (int q=0;q<4;q++) o[q] = f2bf(tile[j0+q][i]);
  } else {
    int e = (b-9984)*256 + t; if (e>=Ee) return;
    int s = src[e], d = dst[e];
    atomicAdd(&indeg[d],1);
    unsigned int key = (unsigned int)s*Nn + (unsigned int)d;
    unsigned int bit = 1u<<(key&31);
    unsigned int old = atomicOr(&bitmap[key>>5], bit);
    int f = (old & bit) ? 0 : 1;
    flag[e] = f;
    if (f) atomicAdd(&cnt_s[s],1);
  }
}

// ---------------- bf16 MFMA GEMM: C = A@B^T, 64(M)x128(N) tile, LDS double-buffer ----------------
__global__ __launch_bounds__(256) void gemm_bf(
    const ushort* __restrict__ A, const ushort* __restrict__ B,
    const ushort* Res, ushort* Cb,
    int M, int N, int K, int relu_res)
{
  __shared__ __align__(16) ushort Ah[2][2048];   // 64 rows x 32 k
  __shared__ __align__(16) ushort Bh[2][4096];   // 128 rows x 32 k
  int t = threadIdx.x;
  int m0 = blockIdx.y*64, n0 = blockIdx.x*128;
  int srA = t>>2, kqA = t&3;
  const ushort* pA = A + (size_t)(m0+srA)*K + kqA*8;
  int wA = (kqA*64 + srA)*8;
  int srB = t>>1, cB = t&1;
  const ushort* pB = B + (size_t)(n0+srB)*K + cB*16;
  int wB0 = ((2*cB)*128 + srB)*8;
  int wB1 = wB0 + 1024;

  int wave = t>>6, lane = t&63;
  int wm = (wave&1)*32, wn = (wave>>1)*64;
  int lm = lane&15, quad = lane>>4;

  ffrag acc[2][4];
  #pragma unroll
  for (int i=0;i<2;i++){
    #pragma unroll
    for (int j=0;j<4;j++) acc[i][j] = (ffrag){0.f,0.f,0.f,0.f};
  }

  uint4 ra  = *(const uint4*)(pA);
  uint4 rb0 = *(const uint4*)(pB);  uint4 rb1 = *(const uint4*)(pB+8);
  *(uint4*)&Ah[0][wA]  = ra;
  *(uint4*)&Bh[0][wB0] = rb0; *(uint4*)&Bh[0][wB1] = rb1;
  if (K > 32){
    ra  = *(const uint4*)(pA+32);
    rb0 = *(const uint4*)(pB+32); rb1 = *(const uint4*)(pB+40);
  }
  __syncthreads();

  for (int k0 = 0; k0 < K; k0 += 32){
    int cur = (k0>>5)&1, nxt = cur^1;
    bfrag af[2];
    #pragma unroll
    for (int mt=0; mt<2; mt++)
      af[mt] = *(const bfrag*)&Ah[cur][(quad*64 + wm + mt*16 + lm)*8];
    #pragma unroll
    for (int nt=0; nt<4; nt++){
      bfrag bf = *(const bfrag*)&Bh[cur][(quad*128 + wn + nt*16 + lm)*8];
      #pragma unroll
      for (int mt=0; mt<2; mt++)
        acc[mt][nt] = __builtin_amdgcn_mfma_f32_16x16x32_bf16(af[mt], bf, acc[mt][nt], 0,0,0);
    }
    if (k0+32 < K){
      *(uint4*)&Ah[nxt][wA]  = ra;
      *(uint4*)&Bh[nxt][wB0] = rb0; *(uint4*)&Bh[nxt][wB1] = rb1;
      if (k0+64 < K){
        ra  = *(const uint4*)(pA+k0+64);
        rb0 = *(const uint4*)(pB+k0+64); rb1 = *(const uint4*)(pB+k0+72);
      }
    }
    __syncthreads();
  }

  #pragma unroll
  for (int mt=0; mt<2; mt++){
    #pragma unroll
    for (int nt=0; nt<4; nt++){
      #pragma unroll
      for (int r=0;r<4;r++){
        int grow = m0 + wm + mt*16 + quad*4 + r;
        int gcol = n0 + wn + nt*16 + lm;
        size_t off = (size_t)grow*N + gcol;
        float v = acc[mt][nt][r];
        if (relu_res) v = fmaxf(v,0.f) + bf2f(Res[off]);
        Cb[off] = f2bf(v);
      }
    }
  }
}

// ---------------- attention logits per (node,head) ----------------
__global__ __launch_bounds__(256) void compute_lg(const ushort* __restrict__ hbf,
    const float* __restrict__ a_src, const float* __restrict__ a_dst,
    float* __restrict__ lgs, float* __restrict__ lgd){
  int n = blockIdx.x; int t = threadIdx.x;
  int hd = t>>6, lane = t&63;
  uint4 g = *(const uint4*)(hbf + (size_t)n*FW + hd*HIDC + lane*8);
  float h[8] = {0,0,0,0,0,0,0,0};
  fma8(h, g, 1.0f);
  float4 as0 = *(const float4*)(a_src + hd*HIDC + lane*8);
  float4 as1 = *(const float4*)(a_src + hd*HIDC + lane*8 + 4);
  float4 ad0 = *(const float4*)(a_dst + hd*HIDC + lane*8);
  float4 ad1 = *(const float4*)(a_dst + hd*HIDC + lane*8 + 4);
  float s1 = h[0]*as0.x + h[1]*as0.y + h[2]*as0.z + h[3]*as0.w
           + h[4]*as1.x + h[5]*as1.y + h[6]*as1.z + h[7]*as1.w;
  float s2 = h[0]*ad0.x + h[1]*ad0.y + h[2]*ad0.z + h[3]*ad0.w
           + h[4]*ad1.x + h[5]*ad1.y + h[6]*ad1.z + h[7]*ad1.w;
  for (int off=32; off; off>>=1){ s1 += __shfl_down(s1,off); s2 += __shfl_down(s2,off); }
  if (lane==0){ lgs[n*HEADS+hd]=s1; lgd[n*HEADS+hd]=s2; }
}

// ---------------- scan3: block0 scan indeg; block1 scan cnt_s + dinv; block2 goff ----------------
__global__ __launch_bounds__(1024) void scan3(const int* __restrict__ indeg, int* __restrict__ rp_d,
    const int* __restrict__ cnt_s, int* __restrict__ rp_s, float* __restrict__ dinv,
    const int* __restrict__ batch, int* __restrict__ goff){
  __shared__ int sums[1024];
  __shared__ int cnt2[GG];
  int t = threadIdx.x;
  if (blockIdx.x == 2){
    if (t<GG) cnt2[t]=0;
    __syncthreads();
    for (int i=t;i<Nn;i+=1024) atomicAdd(&cnt2[batch[i]],1);
    __syncthreads();
    if (t==0){ int run=0; for (int g=0; g<GG; g++){ goff[g]=run; run+=cnt2[g]; } goff[GG]=run; }
    return;
  }
  const int* cnt = blockIdx.x ? cnt_s : indeg;
  int* rowptr    = blockIdx.x ? rp_s  : rp_d;
  int v[4]; int s=0;
  #pragma unroll
  for (int i=0;i<4;i++){ int idx=t*4+i; v[i] = cnt[idx]; s+=v[i]; }
  sums[t]=s; __syncthreads();
  for (int off=1; off<1024; off<<=1){
    int other = (t>=off)? sums[t-off] : 0;
    __syncthreads();
    sums[t] += other;
    __syncthreads();
  }
  int run = (t>0)? sums[t-1] : 0;
  #pragma unroll
  for (int i=0;i<4;i++){
    int idx=t*4+i; rowptr[idx]=run; run+=v[i];
    if (blockIdx.x) dinv[idx] = 1.0f/sqrtf((float)(1+v[i]));
  }
  if (t==1023) rowptr[Nn]=sums[1023];
}

// ---------------- fused edge pass 2: scatter dst-CSR (src vals) + src-CSR (col,dinv) ----------------
__global__ __launch_bounds__(256) void edge_pass2(const int* __restrict__ src, const int* __restrict__ dst,
    const int* __restrict__ flag,
    const int* __restrict__ rp_d, int* __restrict__ fill_d, int* __restrict__ slist,
    const int* __restrict__ rp_s, int* __restrict__ fill_s, int2* __restrict__ cw,
    const float* __restrict__ dinv){
  int e = blockIdx.x*256+threadIdx.x; if (e>=Ee) return;
  int s = src[e], d = dst[e];
  int p = atomicAdd(&fill_d[d],1); slist[rp_d[d]+p] = s;
  if (flag[e]){
    int q = atomicAdd(&fill_s[s],1);
    cw[rp_s[s]+q] = make_int2(d, __float_as_int(dinv[d]));
  }
}

// ---------------- GAT softmax-aggregate: block = (4 nodes) x (1 head), wave = node ----------------
// Pass 3 uses scalar-uniform edge indexing (no shfl): per-wave CSR row, alpha recomputed per lane.
__global__ __launch_bounds__(256) void gat_aggregate(const ushort* __restrict__ hbf,
    const float* __restrict__ lgs, const float* __restrict__ lgd,
    const int* __restrict__ rowptr, const int* __restrict__ slist,
    ushort* __restrict__ Hbf){
  int t = threadIdx.x;
  int wv = __builtin_amdgcn_readfirstlane(t>>6);
  int lane = t&63;
  int b = blockIdx.x;
  int hd = __builtin_amdgcn_readfirstlane(b & 3);
  int n = ((b>>2)<<2) + wv;
  int beg = __builtin_amdgcn_readfirstlane(rowptr[n]);
  int end = __builtin_amdgcn_readfirstlane(rowptr[n+1]);
  int deg = end - beg;
  float ldst = lgd[n*HEADS+hd];
  // ---- single-pass online softmax (m,z), lane-parallel ----
  float m_ = -3.4e38f, z_ = 0.f;
  for (int i=lane; i<deg; i+=64){
    int s = slist[beg+i];
    float v = lgs[s*HEADS+hd] + ldst;
    v = v>0.f ? v : 0.2f*v;
    float mn = fmaxf(m_, v);
    z_ = z_*__expf(m_-mn) + __expf(v-mn);
    m_ = mn;
  }
  for (int o=32;o;o>>=1){
    float mo = __shfl_down(m_,o), zo = __shfl_down(z_,o);
    float mn = fmaxf(m_, mo);
    z_ = z_*__expf(m_-mn) + zo*__expf(mo-mn);
    m_ = mn;
  }
  float mx = __shfl(m_,0);
  float zs = __shfl(z_,0);
  float inv = 1.f/(zs+1e-16f);
  // ---- weighted accumulate: scalar edge loop, 8x gather ILP ----
  float acc[8] = {0,0,0,0,0,0,0,0};
  const ushort* hb = hbf + hd*HIDC + lane*8;
  int i = beg;
  for (; i+8<=end; i+=8){
    int s[8]; uint4 g[8];
    #pragma unroll
    for (int q=0;q<8;q++) s[q] = slist[i+q];
    #pragma unroll
    for (int q=0;q<8;q++) g[q] = *(const uint4*)(hb + (size_t)s[q]*FW);
    #pragma unroll
    for (int q=0;q<8;q++){
      float v = lgs[s[q]*HEADS+hd] + ldst; v = v>0.f ? v : 0.2f*v;
      fma8(acc, g[q], __expf(v-mx)*inv);
    }
  }
  for (; i<end; i++){
    int s = slist[i];
    uint4 g = *(const uint4*)(hb + (size_t)s*FW);
    float v = lgs[s*HEADS+hd] + ldst; v = v>0.f ? v : 0.2f*v;
    fma8(acc, g, __expf(v-mx)*inv);
  }
  size_t off = (size_t)n*FW + hd*HIDC + lane*8;
  pack8(Hbf + off, acc);
}

// ---------------- SpMM: block = (4 nodes) x (1 chunk); scalar-uniform edge loop ----------------
__global__ __launch_bounds__(256) void spmm_bf(const ushort* __restrict__ Hbf,
    ushort* __restrict__ Phi,
    const int* __restrict__ rowptr, const int2* __restrict__ cw, const float* __restrict__ dinv){
  int t = threadIdx.x;
  int wv = __builtin_amdgcn_readfirstlane(t>>6);
  int lane = t&63;
  int b = blockIdx.x;
  int ck = __builtin_amdgcn_readfirstlane(b & 3);
  int n = ((b>>2)<<2) + wv;
  int f = (ck<<9) + lane*8;
  float di = dinv[n];
  float acc[8] = {0,0,0,0,0,0,0,0};
  const ushort* hb = Hbf + f;
  uint4 self = *(const uint4*)(hb + (size_t)n*FW);
  fma8(acc, self, di*di);
  int beg = __builtin_amdgcn_readfirstlane(rowptr[n]);
  int end = __builtin_amdgcn_readfirstlane(rowptr[n+1]);
  int i = beg;
  for (; i+8<=end; i+=8){
    int2 e[8]; uint4 g[8];
    #pragma unroll
    for (int q=0;q<8;q++) e[q] = cw[i+q];
    #pragma unroll
    for (int q=0;q<8;q++) g[q] = *(const uint4*)(hb + (size_t)e[q].x*FW);
    #pragma unroll
    for (int q=0;q<8;q++) fma8(acc, g[q], di*__int_as_float(e[q].y));
  }
  for (; i<end; i++){
    int2 e = cw[i];
    uint4 g = *(const uint4*)(hb + (size_t)e.x*FW);
    fma8(acc, g, di*__int_as_float(e.y));
  }
  pack8(Phi + (size_t)n*FW + f, acc);
}

// ---------------- pooling ----------------
__global__ __launch_bounds__(256) void pool_accum(const ushort* __restrict__ Hb,
    const int* __restrict__ batch, float* __restrict__ psum){
  int d2 = blockIdx.y*256 + threadIdx.x;   // feature-pair index
  int n0 = blockIdx.x*32;
  int g = batch[n0];
  float s0 = 0.f, s1 = 0.f;
  for (int k=0;k<32;k++){
    int n = n0+k;
    int gn = batch[n];
    if (gn != g){
      atomicAdd(&psum[(size_t)g*FW + d2*2],   s0);
      atomicAdd(&psum[(size_t)g*FW + d2*2+1], s1);
      s0=0.f; s1=0.f; g=gn;
    }
    uint v = *(const uint*)(Hb + (size_t)n*FW + d2*2);
    s0 += bf2f((ushort)(v&0xffff));
    s1 += bf2f((ushort)(v>>16));
  }
  atomicAdd(&psum[(size_t)g*FW + d2*2],   s0);
  atomicAdd(&psum[(size_t)g*FW + d2*2+1], s1);
}
__global__ __launch_bounds__(256) void final_out(const float* __restrict__ psum,
    const int* __restrict__ goff,
    const float* __restrict__ fc_w, const float* __restrict__ fc_b, float* __restrict__ out){
  int g = blockIdx.x; int t = threadIdx.x;
  float cinv = 0.25f / fmaxf((float)(goff[g+1]-goff[g]), 1.f);
  float p = 0.f;
  for (int d=t; d<HIDC; d+=256){
    float f = cinv*(psum[(size_t)g*FW+d] + psum[(size_t)g*FW+HIDC+d]
                  + psum[(size_t)g*FW+2*HIDC+d] + psum[(size_t)g*FW+3*HIDC+d]);
    p += f*fc_w[d];
  }
  __shared__ float red[4];
  for (int off=32; off; off>>=1) p += __shfl_down(p,off);
  if ((t&63)==0) red[t>>6]=p;
  __syncthreads();
  if (t==0) out[g] = red[0]+red[1]+red[2]+red[3] + fc_b[0];
}

extern "C" void kernel_launch(void* const* d_in, const int* in_sizes, int n_in,
                              void* d_out, int out_size, void* d_ws, size_t ws_size,
                              hipStream_t stream){
  const float* x      = (const float*)d_in[0];
  const int*   ei     = (const int*)d_in[1];
  const int*   batch  = (const int*)d_in[2];
  const float* W_gat  = (const float*)d_in[3];
  const float* a_src  = (const float*)d_in[4];
  const float* a_dst  = (const float*)d_in[5];
  const float* W_gcn  = (const float*)d_in[6];
  const float* fc_w   = (const float*)d_in[7];
  const float* fc_b   = (const float*)d_in[8];
  float* out = (float*)d_out;
  const int* src = ei;
  const int* dst = ei + Ee;

  char* w = (char*)d_ws;
  size_t off = 0;
  auto alloc = [&](size_t bytes)->char*{ char* p = w + off; off = (off + bytes + 255) & ~(size_t)255; return p; };
  ushort* hbf    = (ushort*)alloc((size_t)Nn*FW*2);       // GAT projection; REUSED as Phi
  ushort* Hbf    = (ushort*)alloc((size_t)Nn*FW*2);       // bf16 node features H (residual trunk)
  ushort* Xbf    = (ushort*)alloc((size_t)Nn*INC*2);
  ushort* WgatT  = (ushort*)alloc((size_t)HEADS*INC*HIDC*2);
  ushort* WgcnT  = (ushort*)alloc((size_t)NLAY*HIDC*HIDC*2);
  float* lgs    = (float*)alloc((size_t)Nn*HEADS*4);
  float* lgd    = (float*)alloc((size_t)Nn*HEADS*4);
  // ---- contiguous zero-init region (single memset) ----
  int* indeg    = (int*)alloc(Nn*4);                      // 16 KB
  int* fill_d   = (int*)alloc(Nn*4);                      // 16 KB
  int* cnt_s    = (int*)alloc(Nn*4);                      // 16 KB
  int* fill_s   = (int*)alloc(Nn*4);                      // 16 KB
  float* psum   = (float*)alloc((size_t)GG*FW*4);         // 128 KB
  unsigned int* bitmap = (unsigned int*)alloc((size_t)Nn*Nn/8);  // 2 MB
  size_t zero_bytes = (size_t)Nn*4*4 + (size_t)GG*FW*4 + (size_t)Nn*Nn/8;
  // ---- rest ----
  int* rowptr_d = (int*)alloc((Nn+1)*4);
  int* slist    = (int*)alloc(Ee*4);
  int* rowptr_s = (int*)alloc((Nn+1)*4);
  int2* cwlist  = (int2*)alloc((size_t)Ee*8);
  int* flag     = (int*)alloc(Ee*4);
  float* dinv   = (float*)alloc(Nn*4);
  int* goff     = (int*)alloc((GG+1)*4);
  ushort* Phi   = hbf;

  hipMemsetAsync(indeg, 0, zero_bytes, stream);

  // ---- fused prep (converts + transposes + edge pass 1) ----
  prep<<<10496,256,0,stream>>>(x, Xbf, W_gat, WgatT, W_gcn, WgcnT,
                               src, dst, indeg, bitmap, cnt_s, flag);

  // ---- GAT projection (bf16 MFMA) ----
  gemm_bf<<<dim3(FW/128, Nn/64),256,0,stream>>>(Xbf, WgatT,
      nullptr, hbf, Nn, FW, INC, 0);
  compute_lg<<<Nn,256,0,stream>>>(hbf, a_src, a_dst, lgs, lgd);

  // ---- CSR build ----
  scan3<<<3,1024,0,stream>>>(indeg, rowptr_d, cnt_s, rowptr_s, dinv, batch, goff);
  edge_pass2<<<Ee/256,256,0,stream>>>(src, dst, flag, rowptr_d, fill_d, slist,
                                      rowptr_s, fill_s, cwlist, dinv);
  gat_aggregate<<<Nn,256,0,stream>>>(hbf, lgs, lgd, rowptr_d, slist, Hbf);

  // ---- residual GCN layers (bf16 trunk) ----
  for (int l=0;l<NLAY;l++){
    spmm_bf<<<Nn,256,0,stream>>>(Hbf, Phi, rowptr_s, cwlist, dinv);
    gemm_bf<<<dim3(HIDC/128, (Nn*HEADS)/64),256,0,stream>>>(Phi,
        WgcnT + (size_t)l*HIDC*HIDC,
        Hbf, Hbf, Nn*HEADS, HIDC, HIDC, 1);
  }

  // ---- pooling + FC ----
  pool_accum<<<dim3(Nn/32, FW/512),256,0,stream>>>(Hbf, batch, psum);
  final_out<<<GG,256,0,stream>>>(psum, goff, fc_w, fc_b, out);
}